// Round 4
// baseline (46251.074 us; speedup 1.0000x reference)
//
#include <hip/hip_runtime.h>
#include <hip/hip_bf16.h>
#include <cstdint>
#include <cstddef>

#define D    768
#define G3   2304
#define BS   64
#define SEQ  300
#define TDEC 100
#define TCH  25          // encoder gi chunk length (12 chunks of 25)
#define NCH  12
#define NBLK 256         // persistent-kernel grid: 256 blocks x 256 thr, all resident
#define NH   (D * 64)    // one h-state buffer (fp32 elems)

// barrier layout (u32 words, 128B-spaced lines)
#define BAR_GRP(g)  ((g) * 32)          // 8 group arrival counters
#define BAR_TOP     256                 // top-level arrival counter
#define BAR_GEN0    288                 // root release flag
#define BAR_GENL(g) (320 + (g) * 32)    // per-group release flags
#define BAR_SIZE    1024                // u32 words per barrier instance

typedef unsigned int u32;
typedef unsigned long long u64;

__device__ __forceinline__ float sigf(float x) { return 1.0f / (1.0f + __expf(-x)); }
__device__ __forceinline__ float tanhfast(float x) {
    float e = __expf(2.0f * x);
    return 1.0f - 2.0f / (e + 1.0f);
}
__device__ __forceinline__ void bf2x(u32 u, float& a, float& b) {
    union { u32 i; float f; } xx, yy;
    xx.i = u << 16; yy.i = u & 0xffff0000u; a = xx.f; b = yy.f;
}

#define DOT4(acc, wv, x0, x1, x2, x3) \
    acc = fmaf((wv).x,(x0), fmaf((wv).y,(x1), fmaf((wv).z,(x2), fmaf((wv).w,(x3),(acc)))))

// ---------- coherent (IF-level) access helpers ----------
__device__ __forceinline__ void stG(float* p, float v) {
    __hip_atomic_store(p, v, __ATOMIC_RELAXED, __HIP_MEMORY_SCOPE_AGENT);
}
__device__ __forceinline__ void stG64(u64* p, u64 v) {
    __hip_atomic_store(p, v, __ATOMIC_RELAXED, __HIP_MEMORY_SCOPE_AGENT);
}
__device__ __forceinline__ float ldGf(const float* p) {
    return __hip_atomic_load(p, __ATOMIC_RELAXED, __HIP_MEMORY_SCOPE_AGENT);
}
__device__ __forceinline__ u32 ldGu(const u32* p) {
    return __hip_atomic_load(p, __ATOMIC_RELAXED, __HIP_MEMORY_SCOPE_AGENT);
}
__device__ __forceinline__ u32 f2bfu(float f) {
    __hip_bfloat16 h = __float2bfloat16(f);
    unsigned short s; __builtin_memcpy(&s, &h, 2); return (u32)s;
}
__device__ __forceinline__ float bfsel(u32 w, int sh) {
    union { u32 i; float f; } u; u.i = ((w >> sh) & 0xffffu) << 16; return u.f;
}

// ---------------- grid barrier: 2-level arrival tree + 2-level release tree ----------------
// No cache-maintenance ops; all protocol words relaxed agent-scope (IF coherence point).
// Arrival: block adds to its group counter (32 blocks/group, 8 groups, separate lines);
// group-last adds to top; top-last stores gen0. Release: group-lasts poll gen0 (<=7
// pollers) and fan out to genL[g]; everyone else polls genL[own group] (<=31 pollers/line).
// All counters monotonic -> no reset. __syncthreads before arrival drains each wave's
// write-through stores (compiler emits s_waitcnt vmcnt(0) before s_barrier).
__device__ __forceinline__ void gridbar(u32* B, u32 idx) {
    __builtin_amdgcn_fence(__ATOMIC_RELEASE, "workgroup");
    __syncthreads();
    if (threadIdx.x == 0) {
        const u32 g = blockIdx.x >> 5;
        u32 old = __hip_atomic_fetch_add(&B[BAR_GRP(g)], 1u, __ATOMIC_RELAXED, __HIP_MEMORY_SCOPE_AGENT);
        if (old == idx * 32u - 1u) {
            u32 o2 = __hip_atomic_fetch_add(&B[BAR_TOP], 1u, __ATOMIC_RELAXED, __HIP_MEMORY_SCOPE_AGENT);
            if (o2 == idx * 8u - 1u) {
                __hip_atomic_store(&B[BAR_GEN0], idx, __ATOMIC_RELAXED, __HIP_MEMORY_SCOPE_AGENT);
            } else {
                while (__hip_atomic_load(&B[BAR_GEN0], __ATOMIC_RELAXED, __HIP_MEMORY_SCOPE_AGENT) < idx)
                    __builtin_amdgcn_s_sleep(4);
            }
            __hip_atomic_store(&B[BAR_GENL(g)], idx, __ATOMIC_RELAXED, __HIP_MEMORY_SCOPE_AGENT);
        } else {
            while (__hip_atomic_load(&B[BAR_GENL(g)], __ATOMIC_RELAXED, __HIP_MEMORY_SCOPE_AGENT) < idx)
                __builtin_amdgcn_s_sleep(8);
        }
    }
    __syncthreads();
}

// ---------------- kPrep: dec_Wih split, init h0/last0, zero barrier words ----------------
__global__ __launch_bounds__(256) void kPrep(
    const float* __restrict__ decWih,
    float* __restrict__ Wc, float* __restrict__ W0,
    float* __restrict__ hSeq0, float* __restrict__ hDs0,
    float* __restrict__ lastP, u32* __restrict__ barW)
{
    const int NW = G3 * 769;         // 1771776
    const int NB = 2 * BAR_SIZE;
    const int TOT = NW + 2 * NH + 64 + NB;
    const int stride = gridDim.x * blockDim.x;
    for (int u = blockIdx.x * blockDim.x + threadIdx.x; u < TOT; u += stride) {
        if (u < NW) {
            int g = u / 769; int c = u % 769;
            float w = decWih[u];
            if (c == 0) W0[g] = w; else Wc[(size_t)g * D + (c - 1)] = w;
        } else if (u < NW + NH) {
            hSeq0[u - NW] = 0.0f;
        } else if (u < NW + 2 * NH) {
            hDs0[u - NW - NH] = 0.0f;
        } else if (u < NW + 2 * NH + 64) {
            lastP[u - NW - 2 * NH] = 0.0f;   // last[t=0] = 0
        } else {
            barW[u - NW - 2 * NH - 64] = 0;
        }
    }
}

// ---------------- gi tile: gi[t][gj][b] = (x[b,t,:]+pe[t,:]) . Wih[gj,:]  (bf16, IF-write) ----------------
__device__ __forceinline__ void gi_tile(
    const float* __restrict__ x, const float* __restrict__ Wih,
    __hip_bfloat16* __restrict__ giB, float* __restrict__ As, float* __restrict__ Bs,
    int m0, int tc, int t)
{
    const int tid = threadIdx.x;
    const int lr = tid >> 2;
    const int lk = (tid & 3) * 4;
    const int tm = (tid >> 4) * 4;
    const int tn = (tid & 15) * 4;
    const float tf = (float)t;

    float acc[4][4];
    #pragma unroll
    for (int i = 0; i < 4; ++i)
        #pragma unroll
        for (int j = 0; j < 4; ++j) acc[i][j] = 0.f;

    for (int kc = 0; kc < D; kc += 16) {
        const float4 a4 = *(const float4*)(Wih + (size_t)(m0 + lr) * D + kc + lk);
        float4 b4 = *(const float4*)(x + ((size_t)lr * SEQ + t) * D + kc + lk);
        const int i0 = (kc + lk) >> 1;
        const float dv0 = __expf(-0.0239852614f * (float)i0);
        const float dv1 = __expf(-0.0239852614f * (float)(i0 + 1));
        float s0, c0, s1, c1;
        __sincosf(tf * dv0, &s0, &c0);
        __sincosf(tf * dv1, &s1, &c1);
        b4.x += s0; b4.y += c0; b4.z += s1; b4.w += c1;
        As[(lk + 0) * 64 + lr] = a4.x; As[(lk + 1) * 64 + lr] = a4.y;
        As[(lk + 2) * 64 + lr] = a4.z; As[(lk + 3) * 64 + lr] = a4.w;
        Bs[(lk + 0) * 64 + lr] = b4.x; Bs[(lk + 1) * 64 + lr] = b4.y;
        Bs[(lk + 2) * 64 + lr] = b4.z; Bs[(lk + 3) * 64 + lr] = b4.w;
        __syncthreads();
        #pragma unroll
        for (int k = 0; k < 16; ++k) {
            const float4 av = *(const float4*)(As + k * 64 + tm);
            const float4 bv = *(const float4*)(Bs + k * 64 + tn);
            acc[0][0] = fmaf(av.x, bv.x, acc[0][0]); acc[0][1] = fmaf(av.x, bv.y, acc[0][1]);
            acc[0][2] = fmaf(av.x, bv.z, acc[0][2]); acc[0][3] = fmaf(av.x, bv.w, acc[0][3]);
            acc[1][0] = fmaf(av.y, bv.x, acc[1][0]); acc[1][1] = fmaf(av.y, bv.y, acc[1][1]);
            acc[1][2] = fmaf(av.y, bv.z, acc[1][2]); acc[1][3] = fmaf(av.y, bv.w, acc[1][3]);
            acc[2][0] = fmaf(av.z, bv.x, acc[2][0]); acc[2][1] = fmaf(av.z, bv.y, acc[2][1]);
            acc[2][2] = fmaf(av.z, bv.z, acc[2][2]); acc[2][3] = fmaf(av.z, bv.w, acc[2][3]);
            acc[3][0] = fmaf(av.w, bv.x, acc[3][0]); acc[3][1] = fmaf(av.w, bv.y, acc[3][1]);
            acc[3][2] = fmaf(av.w, bv.z, acc[3][2]); acc[3][3] = fmaf(av.w, bv.w, acc[3][3]);
        }
        __syncthreads();
    }
    #pragma unroll
    for (int i = 0; i < 4; ++i) {
        u32 lo = f2bfu(acc[i][0]) | (f2bfu(acc[i][1]) << 16);
        u32 hi = f2bfu(acc[i][2]) | (f2bfu(acc[i][3]) << 16);
        u64 v = ((u64)hi << 32) | (u64)lo;
        stG64((u64*)(giB + ((size_t)tc * G3 + m0 + tm + i) * 64 + tn), v);
    }
}

// ---------------- encoder recurrence step (blocks 0..191, 4 waves = 4 j-rows) ----------------
__device__ __forceinline__ void enc_step(
    const __hip_bfloat16* __restrict__ giT, const float* __restrict__ Whh,
    const float* __restrict__ bih, const float* __restrict__ bhh,
    const float* __restrict__ hrd, float* __restrict__ hwr,
    __hip_bfloat16* __restrict__ encB, int t, float* __restrict__ lds_h)
{
    const int tid = threadIdx.x;
    const int b   = tid & 63;
    const int jw  = __builtin_amdgcn_readfirstlane((int)(blockIdx.x * 4 + (tid >> 6)));

    const float* whr = Whh + (size_t)jw * D;
    const float* whz = Whh + (size_t)(768 + jw) * D;
    const float* whn = Whh + (size_t)(1536 + jw) * D;

    float ahr = 0.f, ahz = 0.f, ahn = 0.f;
    for (int kc = 0; kc < D; kc += 64) {
        const float4* gh = (const float4*)(hrd + kc * 64);
        float4* lh = (float4*)lds_h;
        #pragma unroll
        for (int it = 0; it < 4; ++it) lh[tid + 256 * it] = gh[tid + 256 * it];
        __syncthreads();
        #pragma unroll
        for (int kk = 0; kk < 64; kk += 4) {
            const float4 v3 = *(const float4*)(whr + kc + kk);
            const float4 v4 = *(const float4*)(whz + kc + kk);
            const float4 v5 = *(const float4*)(whn + kc + kk);
            const float h0 = lds_h[(kk + 0) * 64 + b];
            const float h1 = lds_h[(kk + 1) * 64 + b];
            const float h2 = lds_h[(kk + 2) * 64 + b];
            const float h3 = lds_h[(kk + 3) * 64 + b];
            DOT4(ahr, v3, h0, h1, h2, h3);
            DOT4(ahz, v4, h0, h1, h2, h3);
            DOT4(ahn, v5, h0, h1, h2, h3);
        }
        __syncthreads();
    }
    const u32* gp = (const u32*)giT;
    const int bo = b >> 1, sh = (b & 1) << 4;
    const u32 w0 = ldGu(gp + (size_t)jw * 32 + bo);
    const u32 w1 = ldGu(gp + (size_t)(768 + jw) * 32 + bo);
    const u32 w2 = ldGu(gp + (size_t)(1536 + jw) * 32 + bo);
    const float gir = bfsel(w0, sh);
    const float giz = bfsel(w1, sh);
    const float gin = bfsel(w2, sh);
    const float r = sigf(gir + bih[jw] + ahr + bhh[jw]);
    const float z = sigf(giz + bih[768 + jw] + ahz + bhh[768 + jw]);
    const float n = tanhfast(gin + bih[1536 + jw] + r * (ahn + bhh[1536 + jw]));
    const float ho = hrd[jw * 64 + b];
    const float hn = (1.f - z) * n + z * ho;
    stG(hwr + jw * 64 + b, hn);                                   // coalesced write-through
    encB[((size_t)b * SEQ + t) * D + jw] = __float2bfloat16(hn);  // consumed next dispatch
}

// ---------------- kEncPersist: GI folded into recurrence shadow; 301 barriers ----------------
__global__ __launch_bounds__(256) void kEncPersist(
    const float* __restrict__ x, const float* __restrict__ eWih,
    const float* __restrict__ eWhh, const float* __restrict__ ebih,
    const float* __restrict__ ebhh, __hip_bfloat16* __restrict__ giB,
    float* __restrict__ hSeq, __hip_bfloat16* __restrict__ encB, u32* bar)
{
    __shared__ float smem[6144];   // enc_step lds_h: [0,4096); gi As/Bs: [4096,6144)
    const size_t GSZ = (size_t)TCH * G3 * 64;
    u32 bars = 0;
    // prologue: GI for chunk 0 (all blocks)
    for (int job = blockIdx.x; job < 36 * TCH; job += NBLK)
        gi_tile(x, eWih, giB, smem + 4096, smem + 5120, (job % 36) * 64, job / 36, job / 36);
    gridbar(bar, ++bars);
    for (int c = 0; c < NCH; ++c) {
        __hip_bfloat16* gcur = giB + (size_t)(c & 1) * GSZ;
        __hip_bfloat16* gnxt = giB + (size_t)((c + 1) & 1) * GSZ;
        for (int tc = 0; tc < TCH; ++tc) {
            const int t = c * TCH + tc;
            if (blockIdx.x < 192)
                enc_step(gcur + (size_t)tc * G3 * 64, eWhh, ebih, ebhh,
                         hSeq + (size_t)t * NH, hSeq + (size_t)(t + 1) * NH, encB, t, smem);
            if (c + 1 < NCH) {
                // 36 tiles of next chunk's time-slot tc, spread over 36 blocks
                const int base = (tc * 36) & 255;
                const int u = ((int)blockIdx.x - base) & 255;
                if (u < 36)
                    gi_tile(x, eWih, gnxt, smem + 4096, smem + 5120,
                            u * 64, tc, (c + 1) * TCH + tc);
            }
            gridbar(bar, ++bars);
        }
    }
}

// ---------------- kGemmMem: mem = enc @ mW^T + mb  (bf16 A, fp32 B, bf16 out) ----------------
__global__ __launch_bounds__(256) void kGemmMem(
    const __hip_bfloat16* __restrict__ encB, const float* __restrict__ mW,
    const float* __restrict__ mb, __hip_bfloat16* __restrict__ memB)
{
    __shared__ float As[16 * 64];
    __shared__ float Bs[16 * 64];
    const int tid = threadIdx.x;
    const int m0 = blockIdx.y * 64, n0 = blockIdx.x * 64;
    const int lr = tid >> 2;
    const int lk = (tid & 3) * 4;
    const int tm = (tid >> 4) * 4;
    const int tn = (tid & 15) * 4;

    float acc[4][4];
    #pragma unroll
    for (int i = 0; i < 4; ++i)
        #pragma unroll
        for (int j = 0; j < 4; ++j) acc[i][j] = 0.f;

    for (int kc = 0; kc < D; kc += 16) {
        const uint2 ua = *(const uint2*)(encB + (size_t)(m0 + lr) * D + kc + lk);
        float a0, a1, a2, a3;
        bf2x(ua.x, a0, a1); bf2x(ua.y, a2, a3);
        const float4 b4 = *(const float4*)(mW + (size_t)(n0 + lr) * D + kc + lk);
        As[(lk + 0) * 64 + lr] = a0; As[(lk + 1) * 64 + lr] = a1;
        As[(lk + 2) * 64 + lr] = a2; As[(lk + 3) * 64 + lr] = a3;
        Bs[(lk + 0) * 64 + lr] = b4.x; Bs[(lk + 1) * 64 + lr] = b4.y;
        Bs[(lk + 2) * 64 + lr] = b4.z; Bs[(lk + 3) * 64 + lr] = b4.w;
        __syncthreads();
        #pragma unroll
        for (int k = 0; k < 16; ++k) {
            const float4 av = *(const float4*)(As + k * 64 + tm);
            const float4 bv = *(const float4*)(Bs + k * 64 + tn);
            acc[0][0] = fmaf(av.x, bv.x, acc[0][0]); acc[0][1] = fmaf(av.x, bv.y, acc[0][1]);
            acc[0][2] = fmaf(av.x, bv.z, acc[0][2]); acc[0][3] = fmaf(av.x, bv.w, acc[0][3]);
            acc[1][0] = fmaf(av.y, bv.x, acc[1][0]); acc[1][1] = fmaf(av.y, bv.y, acc[1][1]);
            acc[1][2] = fmaf(av.y, bv.z, acc[1][2]); acc[1][3] = fmaf(av.y, bv.w, acc[1][3]);
            acc[2][0] = fmaf(av.z, bv.x, acc[2][0]); acc[2][1] = fmaf(av.z, bv.y, acc[2][1]);
            acc[2][2] = fmaf(av.z, bv.z, acc[2][2]); acc[2][3] = fmaf(av.z, bv.w, acc[2][3]);
            acc[3][0] = fmaf(av.w, bv.x, acc[3][0]); acc[3][1] = fmaf(av.w, bv.y, acc[3][1]);
            acc[3][2] = fmaf(av.w, bv.z, acc[3][2]); acc[3][3] = fmaf(av.w, bv.w, acc[3][3]);
        }
        __syncthreads();
    }
    const float bb0 = mb[n0 + tn + 0], bb1 = mb[n0 + tn + 1];
    const float bb2 = mb[n0 + tn + 2], bb3 = mb[n0 + tn + 3];
    #pragma unroll
    for (int i = 0; i < 4; ++i) {
        __hip_bfloat16* row = memB + (size_t)(m0 + tm + i) * D + n0 + tn;
        row[0] = __float2bfloat16(acc[i][0] + bb0);
        row[1] = __float2bfloat16(acc[i][1] + bb1);
        row[2] = __float2bfloat16(acc[i][2] + bb2);
        row[3] = __float2bfloat16(acc[i][3] + bb3);
    }
}

// ---------------- decoder phase: q (blocks 0..191) -> qTt[b][j] unique per t ----------------
__device__ __forceinline__ void dec_q(
    const float* __restrict__ qW, const float* __restrict__ qb,
    const float* __restrict__ hrd, float* __restrict__ qTt,
    float* __restrict__ lds_h, float* __restrict__ lds_t)
{
    const int tid = threadIdx.x;
    const int b   = tid & 63;
    const int wv  = tid >> 6;
    const int jw  = __builtin_amdgcn_readfirstlane((int)(blockIdx.x * 4 + wv));
    const float* w = qW + (size_t)jw * D;
    float acc = 0.f;
    for (int kc = 0; kc < D; kc += 64) {
        const float4* gh = (const float4*)(hrd + kc * 64);
        float4* lh = (float4*)lds_h;
        #pragma unroll
        for (int it = 0; it < 4; ++it) lh[tid + 256 * it] = gh[tid + 256 * it];
        __syncthreads();
        #pragma unroll
        for (int kk = 0; kk < 64; kk += 4) {
            const float4 w4 = *(const float4*)(w + kc + kk);
            acc = fmaf(w4.x, lds_h[(kk + 0) * 64 + b], acc);
            acc = fmaf(w4.y, lds_h[(kk + 1) * 64 + b], acc);
            acc = fmaf(w4.z, lds_h[(kk + 2) * 64 + b], acc);
            acc = fmaf(w4.w, lds_h[(kk + 3) * 64 + b], acc);
        }
        __syncthreads();
    }
    // transpose 4x64 in LDS, write [b][j] in 8B chunks (16B/line used -> 4x amp only)
    lds_t[b * 4 + wv] = acc + qb[jw];
    __syncthreads();
    if (tid < 128) {
        const int bb = tid >> 1, hf = (tid & 1) * 2;
        float2 v; v.x = lds_t[bb * 4 + hf]; v.y = lds_t[bb * 4 + hf + 1];
        u64 uv; __builtin_memcpy(&uv, &v, 8);
        stG64((u64*)(qTt + (size_t)bb * D + blockIdx.x * 4 + hf), uv);
    }
}

// ---------------- decoder phase: tanh-attention, full seq per batch (blocks 0..63) ----------------
__device__ __forceinline__ void dec_attn(
    const float* __restrict__ qTt, const __hip_bfloat16* __restrict__ memB,
    const __hip_bfloat16* __restrict__ encB, const float* __restrict__ pW,
    const float* __restrict__ pb, float* __restrict__ ctxFt, float* __restrict__ seFt,
    float* __restrict__ sm)
{
    const int tid = threadIdx.x;
    const int b = blockIdx.x;       // < 64
    float* s_q  = sm;
    float* s_pw = sm + 768;
    float* s_cx = sm + 1536;
    float* s_se = sm + 2304;
    for (int i = tid; i < 768; i += 256) {
        s_q[i]  = qTt[(size_t)b * D + i];   // cached read of fresh lines (qTt unique per t)
        s_pw[i] = pW[i];
        s_cx[i] = 0.f;
    }
    if (tid == 0) s_se[0] = 0.f;
    __syncthreads();
    const int lane = tid & 63;
    const int wv   = tid >> 6;
    float cacc[12];
    #pragma unroll
    for (int i = 0; i < 12; ++i) cacc[i] = 0.f;
    float seacc = 0.f;
    const float pbv = pb[0];
    for (int s = wv; s < SEQ; s += 4) {
        const __hip_bfloat16* mrow = memB + ((size_t)b * SEQ + s) * D;
        const __hip_bfloat16* erow = encB + ((size_t)b * SEQ + s) * D;
        float lp = 0.f;
        #pragma unroll
        for (int g = 0; g < 3; ++g) {
            const int d0 = g * 256 + lane * 4;
            const uint2 mu = *(const uint2*)(mrow + d0);
            float m0, m1, m2, m3;
            bf2x(mu.x, m0, m1); bf2x(mu.y, m2, m3);
            const float4 qv = *(const float4*)(s_q + d0);
            const float4 pv = *(const float4*)(s_pw + d0);
            lp = fmaf(pv.x, tanhfast(m0 + qv.x), lp);
            lp = fmaf(pv.y, tanhfast(m1 + qv.y), lp);
            lp = fmaf(pv.z, tanhfast(m2 + qv.z), lp);
            lp = fmaf(pv.w, tanhfast(m3 + qv.w), lp);
        }
        #pragma unroll
        for (int o = 32; o > 0; o >>= 1) lp += __shfl_xor(lp, o, 64);
        const float e = __expf(lp + pbv);
        seacc += e;
        #pragma unroll
        for (int g = 0; g < 3; ++g) {
            const int d0 = g * 256 + lane * 4;
            const uint2 eu = *(const uint2*)(erow + d0);
            float e0, e1, e2, e3;
            bf2x(eu.x, e0, e1); bf2x(eu.y, e2, e3);
            cacc[g * 4 + 0] = fmaf(e, e0, cacc[g * 4 + 0]);
            cacc[g * 4 + 1] = fmaf(e, e1, cacc[g * 4 + 1]);
            cacc[g * 4 + 2] = fmaf(e, e2, cacc[g * 4 + 2]);
            cacc[g * 4 + 3] = fmaf(e, e3, cacc[g * 4 + 3]);
        }
    }
    #pragma unroll
    for (int g = 0; g < 3; ++g) {
        const int d0 = g * 256 + lane * 4;
        atomicAdd(&s_cx[d0 + 0], cacc[g * 4 + 0]);
        atomicAdd(&s_cx[d0 + 1], cacc[g * 4 + 1]);
        atomicAdd(&s_cx[d0 + 2], cacc[g * 4 + 2]);
        atomicAdd(&s_cx[d0 + 3], cacc[g * 4 + 3]);
    }
    if (lane == 0) atomicAdd(&s_se[0], seacc);
    __syncthreads();
    // ctxFt[b][k] contiguous -> fully coalesced write-through (no line amplification)
    for (int i = tid; i < 768; i += 256) stG(ctxFt + (size_t)b * D + i, s_cx[i]);
    if (tid == 0) stG(seFt + b, s_se[0]);
}

// ---------------- decoder phase: pred reduce for step t (blocks 64..127, runs in attn shadow) ----------------
__device__ __forceinline__ void dec_reduce(
    const float* __restrict__ ppt, const float* __restrict__ tb,
    float* __restrict__ lastN, float* __restrict__ out, int t, float* __restrict__ sm)
{
    const int b = blockIdx.x - 64;
    const int tid = threadIdx.x;
    float v = 0.f;
    if (tid < 192) v = ppt[(size_t)b * 192 + tid];   // cached fresh, coalesced
    #pragma unroll
    for (int o = 32; o > 0; o >>= 1) v += __shfl_xor(v, o, 64);
    if ((tid & 63) == 0) sm[tid >> 6] = v;
    __syncthreads();
    if (tid == 0) {
        const float p = sm[0] + sm[1] + sm[2] + sm[3] + tb[0];
        out[(size_t)b * TDEC + t] = p;          // single plain store (idempotent)
        stG(lastN + b, p);                      // single write-through store
    }
    __syncthreads();
}

// ---------------- decoder phase: GRU cell + pred partial (blocks 0..191) ----------------
__device__ __forceinline__ void dec_cell(
    const float* __restrict__ Wc, const float* __restrict__ W0,
    const float* __restrict__ dWhh, const float* __restrict__ dbih,
    const float* __restrict__ dbhh, const float* __restrict__ tW,
    const float* __restrict__ ctxFt, const float* __restrict__ seFt,
    const float* __restrict__ lastT, float* __restrict__ ppt,
    const float* __restrict__ hrd, float* __restrict__ hwr,
    float* __restrict__ lds_h, float* __restrict__ lds_c)
{
    const int tid = threadIdx.x;
    const int b   = tid & 63;
    const int q4  = tid >> 6;
    const int jw  = __builtin_amdgcn_readfirstlane((int)(blockIdx.x * 4 + q4));
    const float* whr = dWhh + (size_t)jw * D;
    const float* whz = dWhh + (size_t)(768 + jw) * D;
    const float* whn = dWhh + (size_t)(1536 + jw) * D;
    const float* wcr = Wc + (size_t)jw * D;
    const float* wcz = Wc + (size_t)(768 + jw) * D;
    const float* wcn = Wc + (size_t)(1536 + jw) * D;
    float cir = 0.f, ciz = 0.f, cin_ = 0.f, ahr = 0.f, ahz = 0.f, ahn = 0.f;
    for (int kc = 0; kc < D; kc += 64) {
        const float4* gh = (const float4*)(hrd + kc * 64);
        float4* lh = (float4*)lds_h;
        #pragma unroll
        for (int it = 0; it < 4; ++it) lh[tid + 256 * it] = gh[tid + 256 * it];
        // ctx staging: thread (b,q4) streams one full 64B line of ctxFt[b][kc+16q4..+15]
        {
            const float4* cp = (const float4*)(ctxFt + (size_t)b * D + kc + q4 * 16);
            const float4 c0 = cp[0], c1 = cp[1], c2 = cp[2], c3 = cp[3];
            const int k0 = q4 * 16;
            lds_c[(k0 +  0) * 64 + b] = c0.x; lds_c[(k0 +  1) * 64 + b] = c0.y;
            lds_c[(k0 +  2) * 64 + b] = c0.z; lds_c[(k0 +  3) * 64 + b] = c0.w;
            lds_c[(k0 +  4) * 64 + b] = c1.x; lds_c[(k0 +  5) * 64 + b] = c1.y;
            lds_c[(k0 +  6) * 64 + b] = c1.z; lds_c[(k0 +  7) * 64 + b] = c1.w;
            lds_c[(k0 +  8) * 64 + b] = c2.x; lds_c[(k0 +  9) * 64 + b] = c2.y;
            lds_c[(k0 + 10) * 64 + b] = c2.z; lds_c[(k0 + 11) * 64 + b] = c2.w;
            lds_c[(k0 + 12) * 64 + b] = c3.x; lds_c[(k0 + 13) * 64 + b] = c3.y;
            lds_c[(k0 + 14) * 64 + b] = c3.z; lds_c[(k0 + 15) * 64 + b] = c3.w;
        }
        __syncthreads();
        #pragma unroll
        for (int kk = 0; kk < 64; kk += 4) {
            const float4 v0 = *(const float4*)(wcr + kc + kk);
            const float4 v1 = *(const float4*)(wcz + kc + kk);
            const float4 v2 = *(const float4*)(wcn + kc + kk);
            const float4 v3 = *(const float4*)(whr + kc + kk);
            const float4 v4 = *(const float4*)(whz + kc + kk);
            const float4 v5 = *(const float4*)(whn + kc + kk);
            const float c0 = lds_c[(kk + 0) * 64 + b];
            const float c1 = lds_c[(kk + 1) * 64 + b];
            const float c2 = lds_c[(kk + 2) * 64 + b];
            const float c3 = lds_c[(kk + 3) * 64 + b];
            const float h0 = lds_h[(kk + 0) * 64 + b];
            const float h1 = lds_h[(kk + 1) * 64 + b];
            const float h2 = lds_h[(kk + 2) * 64 + b];
            const float h3 = lds_h[(kk + 3) * 64 + b];
            DOT4(cir, v0, c0, c1, c2, c3);
            DOT4(ciz, v1, c0, c1, c2, c3);
            DOT4(cin_, v2, c0, c1, c2, c3);
            DOT4(ahr, v3, h0, h1, h2, h3);
            DOT4(ahz, v4, h0, h1, h2, h3);
            DOT4(ahn, v5, h0, h1, h2, h3);
        }
        __syncthreads();
    }
    const float inv = 1.f / seFt[b];
    const float lst = lastT[b];
    const float gir = cir * inv + W0[jw] * lst + dbih[jw];
    const float giz = ciz * inv + W0[768 + jw] * lst + dbih[768 + jw];
    const float gin = cin_ * inv + W0[1536 + jw] * lst + dbih[1536 + jw];
    const float r = sigf(gir + ahr + dbhh[jw]);
    const float z = sigf(giz + ahz + dbhh[768 + jw]);
    const float n = tanhfast(gin + r * (ahn + dbhh[1536 + jw]));
    const float ho = hrd[jw * 64 + b];
    const float hn = (1.f - z) * n + z * ho;
    stG(hwr + jw * 64 + b, hn);

    // pred partial: ppt[b][bid] = sum over this block's 4 j's (NO global atomics)
    __syncthreads();
    lds_h[q4 * 64 + b] = tW[jw] * hn;
    __syncthreads();
    if (tid < 64) {
        const float p = lds_h[tid] + lds_h[64 + tid] + lds_h[128 + tid] + lds_h[192 + tid];
        stG(ppt + (size_t)tid * 192 + blockIdx.x, p);
    }
}

// ---------------- kDecPersist: whole decoder in ONE launch (3 barriers/step) ----------------
__global__ __launch_bounds__(256) void kDecPersist(
    const float* __restrict__ Wc, const float* __restrict__ W0,
    const float* __restrict__ dWhh, const float* __restrict__ dbih,
    const float* __restrict__ dbhh, const float* __restrict__ tW,
    const float* __restrict__ tb, const float* __restrict__ qW,
    const float* __restrict__ qb,
    const __hip_bfloat16* __restrict__ memB, const __hip_bfloat16* __restrict__ encB,
    const float* __restrict__ pW, const float* __restrict__ pb,
    float* __restrict__ qTu, float* __restrict__ ctxF, float* __restrict__ seF,
    float* __restrict__ predP, float* __restrict__ lastP,
    float* __restrict__ hDs, float* __restrict__ out, u32* bar)
{
    __shared__ float smem[8192];
    u32 bars = 0;
    for (int t = 0; t < TDEC; ++t) {
        const float* hr = hDs + (size_t)t * NH;
        float*       hw = hDs + (size_t)(t + 1) * NH;
        if (blockIdx.x < 192)
            dec_q(qW, qb, hr, qTu + (size_t)t * BS * D, smem, smem + 4096);
        gridbar(bar, ++bars);
        if (blockIdx.x < 64)
            dec_attn(qTu + (size_t)t * BS * D, memB, encB, pW, pb,
                     ctxF + (size_t)t * BS * D, seF + (size_t)t * 64, smem);
        else if (blockIdx.x < 128 && t > 0)
            dec_reduce(predP + (size_t)(t - 1) * 64 * 192, tb,
                       lastP + (size_t)t * 64, out, t - 1, smem);
        gridbar(bar, ++bars);
        if (blockIdx.x < 192)
            dec_cell(Wc, W0, dWhh, dbih, dbhh, tW,
                     ctxF + (size_t)t * BS * D, seF + (size_t)t * 64,
                     lastP + (size_t)t * 64, predP + (size_t)t * 64 * 192,
                     hr, hw, smem, smem + 4096);
        gridbar(bar, ++bars);
    }
    // final pred reduce for t=99 (after last barrier; no further consumers in-kernel)
    if (blockIdx.x >= 64 && blockIdx.x < 128)
        dec_reduce(predP + (size_t)(TDEC - 1) * 64 * 192, tb,
                   lastP + (size_t)TDEC * 64, out, TDEC - 1, smem);
}

// ---------------- launch ----------------
extern "C" void kernel_launch(void* const* d_in, const int* in_sizes, int n_in,
                              void* d_out, int out_size, void* d_ws, size_t ws_size,
                              hipStream_t stream) {
    const float* x    = (const float*)d_in[0];
    const float* eWih = (const float*)d_in[1];
    const float* eWhh = (const float*)d_in[2];
    const float* ebih = (const float*)d_in[3];
    const float* ebhh = (const float*)d_in[4];
    const float* dWih = (const float*)d_in[5];
    const float* dWhh = (const float*)d_in[6];
    const float* dbih = (const float*)d_in[7];
    const float* dbhh = (const float*)d_in[8];
    const float* qW   = (const float*)d_in[9];
    const float* qb   = (const float*)d_in[10];
    const float* mW   = (const float*)d_in[11];
    const float* mb   = (const float*)d_in[12];
    const float* pW   = (const float*)d_in[13];
    const float* pb   = (const float*)d_in[14];
    const float* tW   = (const float*)d_in[15];
    const float* tb   = (const float*)d_in[16];
    float* out = (float*)d_out;

    char* w = (char*)d_ws;
    auto alloc = [&](size_t bytes) -> char* {
        char* p = w; w += (bytes + 255) & ~(size_t)255; return p;
    };
    // total ~224 MB
    float* Wc    = (float*)alloc((size_t)G3 * D * 4);                  // 7.1 MB
    float* W0    = (float*)alloc((size_t)G3 * 4);
    __hip_bfloat16* encB = (__hip_bfloat16*)alloc((size_t)BS * SEQ * D * 2);  // 29.5 MB
    __hip_bfloat16* memB = (__hip_bfloat16*)alloc((size_t)BS * SEQ * D * 2);  // 29.5 MB
    __hip_bfloat16* giB  = (__hip_bfloat16*)alloc((size_t)2 * TCH * G3 * 64 * 2); // 14.8 MB (dbuf)
    float* hSeq  = (float*)alloc((size_t)(SEQ + 1) * NH * 4);          // 59.2 MB (unique/step)
    float* hDs   = (float*)alloc((size_t)(TDEC + 1) * NH * 4);         // 19.9 MB (unique/step)
    float* qTu   = (float*)alloc((size_t)TDEC * BS * D * 4);           // 19.7 MB (unique/t)
    float* ctxF  = (float*)alloc((size_t)TDEC * BS * D * 4);           // 19.7 MB (unique/t)
    float* seF   = (float*)alloc((size_t)TDEC * 64 * 4);
    float* predP = (float*)alloc((size_t)TDEC * 64 * 192 * 4);         // 4.9 MB (unique/t)
    float* lastP = (float*)alloc((size_t)(TDEC + 1) * 64 * 4);
    u32*   barW  = (u32*)alloc((size_t)2 * BAR_SIZE * 4);              // [0]=enc, [1]=dec

    kPrep<<<512, 256, 0, stream>>>(dWih, Wc, W0, hSeq, hDs, lastP, barW);
    kEncPersist<<<NBLK, 256, 0, stream>>>(x, eWih, eWhh, ebih, ebhh, giB, hSeq, encB, barW);
    kGemmMem<<<dim3(12, 300), 256, 0, stream>>>(encB, mW, mb, memB);
    kDecPersist<<<NBLK, 256, 0, stream>>>(Wc, W0, dWhh, dbih, dbhh, tW, tb, qW, qb,
                                          memB, encB, pW, pb, qTu, ctxF, seF,
                                          predP, lastP, hDs, out, barW + BAR_SIZE);
}

// Round 5
// 23298.932 us; speedup vs baseline: 1.9851x; 1.9851x over previous
//
#include <hip/hip_runtime.h>
#include <hip/hip_bf16.h>
#include <cstdint>
#include <cstddef>

#define D    768
#define G3   2304
#define BS   64
#define SEQ  300
#define TDEC 100
#define TCH  25          // encoder gi chunk length (12 chunks of 25)
#define NCH  12
#define NBLK 512         // persistent grid: 512 blocks x 256 thr = 2 blocks/CU (2 waves/SIMD)
#define NH   (D * 64)    // one h-state buffer (fp32 elems)

// barrier layout (u32 words, 128B-spaced lines); 16 groups x 32 blocks
#define BAR_GRP(g)  ((g) * 32)          // 16 group arrival counters
#define BAR_TOP     512                 // top-level arrival counter
#define BAR_GEN0    544                 // root release flag
#define BAR_GENL(g) (576 + (g) * 32)    // per-group release flags
#define BAR_SIZE    2048                // u32 words per barrier instance

typedef unsigned int u32;
typedef unsigned long long u64;

__device__ __forceinline__ float sigf(float x) { return 1.0f / (1.0f + __expf(-x)); }
__device__ __forceinline__ float tanhfast(float x) {
    float e = __expf(2.0f * x);
    return 1.0f - 2.0f / (e + 1.0f);
}
__device__ __forceinline__ void bf2x(u32 u, float& a, float& b) {
    union { u32 i; float f; } xx, yy;
    xx.i = u << 16; yy.i = u & 0xffff0000u; a = xx.f; b = yy.f;
}

#define DOT4(acc, wv, x0, x1, x2, x3) \
    acc = fmaf((wv).x,(x0), fmaf((wv).y,(x1), fmaf((wv).z,(x2), fmaf((wv).w,(x3),(acc)))))

// ---------- coherent (IF-level) access helpers ----------
__device__ __forceinline__ void stG(float* p, float v) {
    __hip_atomic_store(p, v, __ATOMIC_RELAXED, __HIP_MEMORY_SCOPE_AGENT);
}
__device__ __forceinline__ void stG64(u64* p, u64 v) {
    __hip_atomic_store(p, v, __ATOMIC_RELAXED, __HIP_MEMORY_SCOPE_AGENT);
}
__device__ __forceinline__ float ldGf(const float* p) {
    return __hip_atomic_load(p, __ATOMIC_RELAXED, __HIP_MEMORY_SCOPE_AGENT);
}
__device__ __forceinline__ u32 ldGu(const u32* p) {
    return __hip_atomic_load(p, __ATOMIC_RELAXED, __HIP_MEMORY_SCOPE_AGENT);
}
__device__ __forceinline__ u32 f2bfu(float f) {
    __hip_bfloat16 h = __float2bfloat16(f);
    unsigned short s; __builtin_memcpy(&s, &h, 2); return (u32)s;
}
__device__ __forceinline__ float bfsel(u32 w, int sh) {
    union { u32 i; float f; } u; u.i = ((w >> sh) & 0xffffu) << 16; return u.f;
}

// ---------------- grid barrier: 2-level arrival + 2-level release, no cache maintenance ----------------
__device__ __forceinline__ void gridbar(u32* B, u32 idx) {
    __builtin_amdgcn_fence(__ATOMIC_RELEASE, "workgroup");   // drains vmcnt; no wbl2/inv
    __syncthreads();
    if (threadIdx.x == 0) {
        const u32 g = blockIdx.x >> 5;          // 16 groups of 32
        u32 old = __hip_atomic_fetch_add(&B[BAR_GRP(g)], 1u, __ATOMIC_RELAXED, __HIP_MEMORY_SCOPE_AGENT);
        if (old == idx * 32u - 1u) {
            u32 o2 = __hip_atomic_fetch_add(&B[BAR_TOP], 1u, __ATOMIC_RELAXED, __HIP_MEMORY_SCOPE_AGENT);
            if (o2 == idx * 16u - 1u) {
                __hip_atomic_store(&B[BAR_GEN0], idx, __ATOMIC_RELAXED, __HIP_MEMORY_SCOPE_AGENT);
            } else {
                while (__hip_atomic_load(&B[BAR_GEN0], __ATOMIC_RELAXED, __HIP_MEMORY_SCOPE_AGENT) < idx)
                    __builtin_amdgcn_s_sleep(4);
            }
            __hip_atomic_store(&B[BAR_GENL(g)], idx, __ATOMIC_RELAXED, __HIP_MEMORY_SCOPE_AGENT);
        } else {
            while (__hip_atomic_load(&B[BAR_GENL(g)], __ATOMIC_RELAXED, __HIP_MEMORY_SCOPE_AGENT) < idx)
                __builtin_amdgcn_s_sleep(8);
        }
    }
    __syncthreads();
}

// ---------------- kPrep ----------------
__global__ __launch_bounds__(256) void kPrep(
    const float* __restrict__ decWih,
    float* __restrict__ Wc, float* __restrict__ W0,
    float* __restrict__ hSeq0, float* __restrict__ hDs0,
    float* __restrict__ lastP, u32* __restrict__ barW)
{
    const int NW = G3 * 769;
    const int NB = 2 * BAR_SIZE;
    const int TOT = NW + 2 * NH + 64 + NB;
    const int stride = gridDim.x * blockDim.x;
    for (int u = blockIdx.x * blockDim.x + threadIdx.x; u < TOT; u += stride) {
        if (u < NW) {
            int g = u / 769; int c = u % 769;
            float w = decWih[u];
            if (c == 0) W0[g] = w; else Wc[(size_t)g * D + (c - 1)] = w;
        } else if (u < NW + NH) {
            hSeq0[u - NW] = 0.0f;
        } else if (u < NW + 2 * NH) {
            hDs0[u - NW - NH] = 0.0f;
        } else if (u < NW + 2 * NH + 64) {
            lastP[u - NW - 2 * NH] = 0.0f;
        } else {
            barW[u - NW - 2 * NH - 64] = 0;
        }
    }
}

// ---------------- gi tile (64x64 tile at (m0, tc); bf16 write-through out) ----------------
__device__ __forceinline__ void gi_tile(
    const float* __restrict__ x, const float* __restrict__ Wih,
    __hip_bfloat16* __restrict__ giB, float* __restrict__ As, float* __restrict__ Bs,
    int m0, int tc, int t)
{
    const int tid = threadIdx.x;
    const int lr = tid >> 2;
    const int lk = (tid & 3) * 4;
    const int tm = (tid >> 4) * 4;
    const int tn = (tid & 15) * 4;
    const float tf = (float)t;

    float acc[4][4];
    #pragma unroll
    for (int i = 0; i < 4; ++i)
        #pragma unroll
        for (int j = 0; j < 4; ++j) acc[i][j] = 0.f;

    for (int kc = 0; kc < D; kc += 16) {
        const float4 a4 = *(const float4*)(Wih + (size_t)(m0 + lr) * D + kc + lk);
        float4 b4 = *(const float4*)(x + ((size_t)lr * SEQ + t) * D + kc + lk);
        const int i0 = (kc + lk) >> 1;
        const float dv0 = __expf(-0.0239852614f * (float)i0);
        const float dv1 = __expf(-0.0239852614f * (float)(i0 + 1));
        float s0, c0, s1, c1;
        __sincosf(tf * dv0, &s0, &c0);
        __sincosf(tf * dv1, &s1, &c1);
        b4.x += s0; b4.y += c0; b4.z += s1; b4.w += c1;
        As[(lk + 0) * 64 + lr] = a4.x; As[(lk + 1) * 64 + lr] = a4.y;
        As[(lk + 2) * 64 + lr] = a4.z; As[(lk + 3) * 64 + lr] = a4.w;
        Bs[(lk + 0) * 64 + lr] = b4.x; Bs[(lk + 1) * 64 + lr] = b4.y;
        Bs[(lk + 2) * 64 + lr] = b4.z; Bs[(lk + 3) * 64 + lr] = b4.w;
        __syncthreads();
        #pragma unroll
        for (int k = 0; k < 16; ++k) {
            const float4 av = *(const float4*)(As + k * 64 + tm);
            const float4 bv = *(const float4*)(Bs + k * 64 + tn);
            acc[0][0] = fmaf(av.x, bv.x, acc[0][0]); acc[0][1] = fmaf(av.x, bv.y, acc[0][1]);
            acc[0][2] = fmaf(av.x, bv.z, acc[0][2]); acc[0][3] = fmaf(av.x, bv.w, acc[0][3]);
            acc[1][0] = fmaf(av.y, bv.x, acc[1][0]); acc[1][1] = fmaf(av.y, bv.y, acc[1][1]);
            acc[1][2] = fmaf(av.y, bv.z, acc[1][2]); acc[1][3] = fmaf(av.y, bv.w, acc[1][3]);
            acc[2][0] = fmaf(av.z, bv.x, acc[2][0]); acc[2][1] = fmaf(av.z, bv.y, acc[2][1]);
            acc[2][2] = fmaf(av.z, bv.z, acc[2][2]); acc[2][3] = fmaf(av.z, bv.w, acc[2][3]);
            acc[3][0] = fmaf(av.w, bv.x, acc[3][0]); acc[3][1] = fmaf(av.w, bv.y, acc[3][1]);
            acc[3][2] = fmaf(av.w, bv.z, acc[3][2]); acc[3][3] = fmaf(av.w, bv.w, acc[3][3]);
        }
        __syncthreads();
    }
    #pragma unroll
    for (int i = 0; i < 4; ++i) {
        u32 lo = f2bfu(acc[i][0]) | (f2bfu(acc[i][1]) << 16);
        u32 hi = f2bfu(acc[i][2]) | (f2bfu(acc[i][3]) << 16);
        u64 v = ((u64)hi << 32) | (u64)lo;
        stG64((u64*)(giB + ((size_t)tc * G3 + m0 + tm + i) * 64 + tn), v);
    }
}

// ---------------- encoder recurrence step (blocks 0..191, 4 waves = 4 j-rows) ----------------
__device__ __forceinline__ void enc_step(
    const __hip_bfloat16* __restrict__ giT, const float* __restrict__ Whh,
    const float* __restrict__ bih, const float* __restrict__ bhh,
    const float* __restrict__ hrd, float* __restrict__ hwr,
    __hip_bfloat16* __restrict__ encB, int t, float* __restrict__ lds_h)
{
    const int tid = threadIdx.x;
    const int b   = tid & 63;
    const int jw  = __builtin_amdgcn_readfirstlane((int)(blockIdx.x * 4 + (tid >> 6)));

    const float* whr = Whh + (size_t)jw * D;
    const float* whz = Whh + (size_t)(768 + jw) * D;
    const float* whn = Whh + (size_t)(1536 + jw) * D;

    float ahr = 0.f, ahz = 0.f, ahn = 0.f;
    for (int kc = 0; kc < D; kc += 64) {
        const float4* gh = (const float4*)(hrd + kc * 64);
        float4* lh = (float4*)lds_h;
        #pragma unroll
        for (int it = 0; it < 4; ++it) lh[tid + 256 * it] = gh[tid + 256 * it];
        __syncthreads();
        #pragma unroll
        for (int kk = 0; kk < 64; kk += 4) {
            const float4 v3 = *(const float4*)(whr + kc + kk);
            const float4 v4 = *(const float4*)(whz + kc + kk);
            const float4 v5 = *(const float4*)(whn + kc + kk);
            const float h0 = lds_h[(kk + 0) * 64 + b];
            const float h1 = lds_h[(kk + 1) * 64 + b];
            const float h2 = lds_h[(kk + 2) * 64 + b];
            const float h3 = lds_h[(kk + 3) * 64 + b];
            DOT4(ahr, v3, h0, h1, h2, h3);
            DOT4(ahz, v4, h0, h1, h2, h3);
            DOT4(ahn, v5, h0, h1, h2, h3);
        }
        __syncthreads();
    }
    const u32* gp = (const u32*)giT;
    const int bo = b >> 1, sh = (b & 1) << 4;
    const u32 w0 = ldGu(gp + (size_t)jw * 32 + bo);
    const u32 w1 = ldGu(gp + (size_t)(768 + jw) * 32 + bo);
    const u32 w2 = ldGu(gp + (size_t)(1536 + jw) * 32 + bo);
    const float gir = bfsel(w0, sh);
    const float giz = bfsel(w1, sh);
    const float gin = bfsel(w2, sh);
    const float r = sigf(gir + bih[jw] + ahr + bhh[jw]);
    const float z = sigf(giz + bih[768 + jw] + ahz + bhh[768 + jw]);
    const float n = tanhfast(gin + bih[1536 + jw] + r * (ahn + bhh[1536 + jw]));
    const float ho = hrd[jw * 64 + b];
    const float hn = (1.f - z) * n + z * ho;
    stG(hwr + jw * 64 + b, hn);
    encB[((size_t)b * SEQ + t) * D + jw] = __float2bfloat16(hn);
}

// ---------------- kEncPersist: round-3 structure (separate GI phases), 512 blocks ----------------
__global__ __launch_bounds__(256) void kEncPersist(
    const float* __restrict__ x, const float* __restrict__ eWih,
    const float* __restrict__ eWhh, const float* __restrict__ ebih,
    const float* __restrict__ ebhh, __hip_bfloat16* __restrict__ giB,
    float* __restrict__ hSeq, __hip_bfloat16* __restrict__ encB, u32* bar)
{
    __shared__ float smem[4096];   // GI: As=[0,1024) Bs=[1024,2048); step: lds_h=[0,4096)
    u32 bars = 0;
    for (int c = 0; c < NCH; ++c) {
        for (int job = blockIdx.x; job < 36 * TCH; job += NBLK)
            gi_tile(x, eWih, giB, smem, smem + 1024,
                    (job % 36) * 64, job / 36, c * TCH + job / 36);
        gridbar(bar, ++bars);
        for (int tc = 0; tc < TCH; ++tc) {
            const int t = c * TCH + tc;
            if (blockIdx.x < 192)
                enc_step(giB + (size_t)tc * G3 * 64, eWhh, ebih, ebhh,
                         hSeq + (size_t)t * NH, hSeq + (size_t)(t + 1) * NH, encB, t, smem);
            gridbar(bar, ++bars);
        }
    }
}

// ---------------- kGemmMem: mem = enc @ mW^T + mb ----------------
__global__ __launch_bounds__(256) void kGemmMem(
    const __hip_bfloat16* __restrict__ encB, const float* __restrict__ mW,
    const float* __restrict__ mb, __hip_bfloat16* __restrict__ memB)
{
    __shared__ float As[16 * 64];
    __shared__ float Bs[16 * 64];
    const int tid = threadIdx.x;
    const int m0 = blockIdx.y * 64, n0 = blockIdx.x * 64;
    const int lr = tid >> 2;
    const int lk = (tid & 3) * 4;
    const int tm = (tid >> 4) * 4;
    const int tn = (tid & 15) * 4;

    float acc[4][4];
    #pragma unroll
    for (int i = 0; i < 4; ++i)
        #pragma unroll
        for (int j = 0; j < 4; ++j) acc[i][j] = 0.f;

    for (int kc = 0; kc < D; kc += 16) {
        const uint2 ua = *(const uint2*)(encB + (size_t)(m0 + lr) * D + kc + lk);
        float a0, a1, a2, a3;
        bf2x(ua.x, a0, a1); bf2x(ua.y, a2, a3);
        const float4 b4 = *(const float4*)(mW + (size_t)(n0 + lr) * D + kc + lk);
        As[(lk + 0) * 64 + lr] = a0; As[(lk + 1) * 64 + lr] = a1;
        As[(lk + 2) * 64 + lr] = a2; As[(lk + 3) * 64 + lr] = a3;
        Bs[(lk + 0) * 64 + lr] = b4.x; Bs[(lk + 1) * 64 + lr] = b4.y;
        Bs[(lk + 2) * 64 + lr] = b4.z; Bs[(lk + 3) * 64 + lr] = b4.w;
        __syncthreads();
        #pragma unroll
        for (int k = 0; k < 16; ++k) {
            const float4 av = *(const float4*)(As + k * 64 + tm);
            const float4 bv = *(const float4*)(Bs + k * 64 + tn);
            acc[0][0] = fmaf(av.x, bv.x, acc[0][0]); acc[0][1] = fmaf(av.x, bv.y, acc[0][1]);
            acc[0][2] = fmaf(av.x, bv.z, acc[0][2]); acc[0][3] = fmaf(av.x, bv.w, acc[0][3]);
            acc[1][0] = fmaf(av.y, bv.x, acc[1][0]); acc[1][1] = fmaf(av.y, bv.y, acc[1][1]);
            acc[1][2] = fmaf(av.y, bv.z, acc[1][2]); acc[1][3] = fmaf(av.y, bv.w, acc[1][3]);
            acc[2][0] = fmaf(av.z, bv.x, acc[2][0]); acc[2][1] = fmaf(av.z, bv.y, acc[2][1]);
            acc[2][2] = fmaf(av.z, bv.z, acc[2][2]); acc[2][3] = fmaf(av.z, bv.w, acc[2][3]);
            acc[3][0] = fmaf(av.w, bv.x, acc[3][0]); acc[3][1] = fmaf(av.w, bv.y, acc[3][1]);
            acc[3][2] = fmaf(av.w, bv.z, acc[3][2]); acc[3][3] = fmaf(av.w, bv.w, acc[3][3]);
        }
        __syncthreads();
    }
    const float bb0 = mb[n0 + tn + 0], bb1 = mb[n0 + tn + 1];
    const float bb2 = mb[n0 + tn + 2], bb3 = mb[n0 + tn + 3];
    #pragma unroll
    for (int i = 0; i < 4; ++i) {
        __hip_bfloat16* row = memB + (size_t)(m0 + tm + i) * D + n0 + tn;
        row[0] = __float2bfloat16(acc[i][0] + bb0);
        row[1] = __float2bfloat16(acc[i][1] + bb1);
        row[2] = __float2bfloat16(acc[i][2] + bb2);
        row[3] = __float2bfloat16(acc[i][3] + bb3);
    }
}

// ---------------- decoder phase: q (blocks 0..191) -> qTt[b][j] unique per t ----------------
__device__ __forceinline__ void dec_q(
    const float* __restrict__ qW, const float* __restrict__ qb,
    const float* __restrict__ hrd, float* __restrict__ qTt,
    float* __restrict__ lds_h, float* __restrict__ lds_t)
{
    const int tid = threadIdx.x;
    const int b   = tid & 63;
    const int wv  = tid >> 6;
    const int jw  = __builtin_amdgcn_readfirstlane((int)(blockIdx.x * 4 + wv));
    const float* w = qW + (size_t)jw * D;
    float acc = 0.f;
    for (int kc = 0; kc < D; kc += 64) {
        const float4* gh = (const float4*)(hrd + kc * 64);
        float4* lh = (float4*)lds_h;
        #pragma unroll
        for (int it = 0; it < 4; ++it) lh[tid + 256 * it] = gh[tid + 256 * it];
        __syncthreads();
        #pragma unroll
        for (int kk = 0; kk < 64; kk += 4) {
            const float4 w4 = *(const float4*)(w + kc + kk);
            acc = fmaf(w4.x, lds_h[(kk + 0) * 64 + b], acc);
            acc = fmaf(w4.y, lds_h[(kk + 1) * 64 + b], acc);
            acc = fmaf(w4.z, lds_h[(kk + 2) * 64 + b], acc);
            acc = fmaf(w4.w, lds_h[(kk + 3) * 64 + b], acc);
        }
        __syncthreads();
    }
    lds_t[b * 4 + wv] = acc + qb[jw];
    __syncthreads();
    if (tid < 128) {
        const int bb = tid >> 1, hf = (tid & 1) * 2;
        float2 v; v.x = lds_t[bb * 4 + hf]; v.y = lds_t[bb * 4 + hf + 1];
        u64 uv; __builtin_memcpy(&uv, &v, 8);
        stG64((u64*)(qTt + (size_t)bb * D + blockIdx.x * 4 + hf), uv);
    }
}

// ---------------- decoder phase: tanh-attention (ALL 512 blocks; b=blk&63, ch=blk>>6 in 0..7) ----------------
// wave handles rows s = ch + 8*wv + 32*i (each s in [0,300) covered exactly once).
// Software prefetch: next row's 6 loads issued before current row's tanh chain.
__device__ __forceinline__ void dec_attn(
    const float* __restrict__ qTt, const __hip_bfloat16* __restrict__ memB,
    const __hip_bfloat16* __restrict__ encB, const float* __restrict__ pW,
    const float* __restrict__ pb, float* __restrict__ ctxP, float* __restrict__ seP,
    float* __restrict__ sm)
{
    const int tid = threadIdx.x;
    const int b  = blockIdx.x & 63;
    const int ch = blockIdx.x >> 6;          // 0..7
    float* s_q  = sm;
    float* s_pw = sm + 768;
    float* s_cx = sm + 1536;
    float* s_se = sm + 2304;
    for (int i = tid; i < 768; i += 256) {
        s_q[i]  = qTt[(size_t)b * D + i];    // fresh lines (unique per t) -> cached safe
        s_pw[i] = pW[i];
        s_cx[i] = 0.f;
    }
    if (tid == 0) s_se[0] = 0.f;
    __syncthreads();
    const int lane = tid & 63;
    const int wv   = tid >> 6;
    const int d0_0 = lane * 4, d0_1 = 256 + lane * 4, d0_2 = 512 + lane * 4;
    // hoist q/pW to registers (constant across rows)
    const float4 qv0 = *(const float4*)(s_q + d0_0);
    const float4 qv1 = *(const float4*)(s_q + d0_1);
    const float4 qv2 = *(const float4*)(s_q + d0_2);
    const float4 pv0 = *(const float4*)(s_pw + d0_0);
    const float4 pv1 = *(const float4*)(s_pw + d0_1);
    const float4 pv2 = *(const float4*)(s_pw + d0_2);
    float cacc[12];
    #pragma unroll
    for (int i = 0; i < 12; ++i) cacc[i] = 0.f;
    float seacc = 0.f;
    const float pbv = pb[0];
    const size_t rowb = (size_t)b * SEQ;
    int s = ch + 8 * wv;
    uint2 mu0, mu1, mu2, eu0, eu1, eu2;
    if (s < SEQ) {
        const __hip_bfloat16* mrow = memB + (rowb + s) * D;
        const __hip_bfloat16* erow = encB + (rowb + s) * D;
        mu0 = *(const uint2*)(mrow + d0_0); mu1 = *(const uint2*)(mrow + d0_1); mu2 = *(const uint2*)(mrow + d0_2);
        eu0 = *(const uint2*)(erow + d0_0); eu1 = *(const uint2*)(erow + d0_1); eu2 = *(const uint2*)(erow + d0_2);
    }
    while (s < SEQ) {
        const int sn = s + 32;
        const bool pf = sn < SEQ;            // wave-uniform
        uint2 nm0, nm1, nm2, ne0, ne1, ne2;
        if (pf) {
            const __hip_bfloat16* mrow = memB + (rowb + sn) * D;
            const __hip_bfloat16* erow = encB + (rowb + sn) * D;
            nm0 = *(const uint2*)(mrow + d0_0); nm1 = *(const uint2*)(mrow + d0_1); nm2 = *(const uint2*)(mrow + d0_2);
            ne0 = *(const uint2*)(erow + d0_0); ne1 = *(const uint2*)(erow + d0_1); ne2 = *(const uint2*)(erow + d0_2);
        }
        float lp = 0.f;
        float m0, m1, m2, m3;
        bf2x(mu0.x, m0, m1); bf2x(mu0.y, m2, m3);
        lp = fmaf(pv0.x, tanhfast(m0 + qv0.x), lp);
        lp = fmaf(pv0.y, tanhfast(m1 + qv0.y), lp);
        lp = fmaf(pv0.z, tanhfast(m2 + qv0.z), lp);
        lp = fmaf(pv0.w, tanhfast(m3 + qv0.w), lp);
        bf2x(mu1.x, m0, m1); bf2x(mu1.y, m2, m3);
        lp = fmaf(pv1.x, tanhfast(m0 + qv1.x), lp);
        lp = fmaf(pv1.y, tanhfast(m1 + qv1.y), lp);
        lp = fmaf(pv1.z, tanhfast(m2 + qv1.z), lp);
        lp = fmaf(pv1.w, tanhfast(m3 + qv1.w), lp);
        bf2x(mu2.x, m0, m1); bf2x(mu2.y, m2, m3);
        lp = fmaf(pv2.x, tanhfast(m0 + qv2.x), lp);
        lp = fmaf(pv2.y, tanhfast(m1 + qv2.y), lp);
        lp = fmaf(pv2.z, tanhfast(m2 + qv2.z), lp);
        lp = fmaf(pv2.w, tanhfast(m3 + qv2.w), lp);
        #pragma unroll
        for (int o = 32; o > 0; o >>= 1) lp += __shfl_xor(lp, o, 64);
        const float e = __expf(lp + pbv);
        seacc += e;
        float e0, e1, e2, e3;
        bf2x(eu0.x, e0, e1); bf2x(eu0.y, e2, e3);
        cacc[0] = fmaf(e, e0, cacc[0]); cacc[1] = fmaf(e, e1, cacc[1]);
        cacc[2] = fmaf(e, e2, cacc[2]); cacc[3] = fmaf(e, e3, cacc[3]);
        bf2x(eu1.x, e0, e1); bf2x(eu1.y, e2, e3);
        cacc[4] = fmaf(e, e0, cacc[4]); cacc[5] = fmaf(e, e1, cacc[5]);
        cacc[6] = fmaf(e, e2, cacc[6]); cacc[7] = fmaf(e, e3, cacc[7]);
        bf2x(eu2.x, e0, e1); bf2x(eu2.y, e2, e3);
        cacc[8]  = fmaf(e, e0, cacc[8]);  cacc[9]  = fmaf(e, e1, cacc[9]);
        cacc[10] = fmaf(e, e2, cacc[10]); cacc[11] = fmaf(e, e3, cacc[11]);
        if (pf) { mu0 = nm0; mu1 = nm1; mu2 = nm2; eu0 = ne0; eu1 = ne1; eu2 = ne2; }
        s = sn;
    }
    #pragma unroll
    for (int g = 0; g < 3; ++g) {
        const int d0 = g * 256 + lane * 4;
        atomicAdd(&s_cx[d0 + 0], cacc[g * 4 + 0]);
        atomicAdd(&s_cx[d0 + 1], cacc[g * 4 + 1]);
        atomicAdd(&s_cx[d0 + 2], cacc[g * 4 + 2]);
        atomicAdd(&s_cx[d0 + 3], cacc[g * 4 + 3]);
    }
    if (lane == 0) atomicAdd(&s_se[0], seacc);
    __syncthreads();
    // partial rows contiguous per block -> coalesced write-through, no amplification
    float* crow = ctxP + (size_t)(ch * 64 + b) * D;
    for (int i = tid; i < 768; i += 256) stG(crow + i, s_cx[i]);
    if (tid == 0) stG(seP + ch * 64 + b, s_se[0]);
}

// ---------------- decoder phase: combine 8 partials -> unique-per-t buffers (blocks 0..63) ----------------
__device__ __forceinline__ void dec_combine(
    const float* __restrict__ ctxP, const float* __restrict__ seP,
    float* __restrict__ ctxCt, float* __restrict__ seCt)
{
    const int b = blockIdx.x;           // < 64
    const int tid = threadIdx.x;
    for (int i = tid; i < 768; i += 256) {
        float s = 0.f;
        #pragma unroll
        for (int ch = 0; ch < 8; ++ch)
            s += ldGf(ctxP + (size_t)(ch * 64 + b) * D + i);
        stG(ctxCt + (size_t)b * D + i, s);   // fresh lines: cell reads cached
    }
    if (tid == 0) {
        float s = 0.f;
        #pragma unroll
        for (int ch = 0; ch < 8; ++ch) s += ldGf(seP + ch * 64 + b);
        stG(seCt + b, s);
    }
}

// ---------------- decoder phase: pred reduce for step t (blocks 448..511, q-phase shadow) ----------------
__device__ __forceinline__ void dec_reduce(
    const float* __restrict__ ppt, const float* __restrict__ tb,
    float* __restrict__ lastN, float* __restrict__ out, int t, float* __restrict__ sm)
{
    const int b = blockIdx.x - 448;
    const int tid = threadIdx.x;
    float v = 0.f;
    if (tid < 192) v = ppt[(size_t)b * 192 + tid];   // fresh lines, coalesced
    #pragma unroll
    for (int o = 32; o > 0; o >>= 1) v += __shfl_xor(v, o, 64);
    if ((tid & 63) == 0) sm[tid >> 6] = v;
    __syncthreads();
    if (tid == 0) {
        const float p = sm[0] + sm[1] + sm[2] + sm[3] + tb[0];
        out[(size_t)b * TDEC + t] = p;          // single plain store
        stG(lastN + b, p);
    }
    __syncthreads();
}

// ---------------- decoder phase: GRU cell + pred partial (blocks 0..191) ----------------
__device__ __forceinline__ void dec_cell(
    const float* __restrict__ Wc, const float* __restrict__ W0,
    const float* __restrict__ dWhh, const float* __restrict__ dbih,
    const float* __restrict__ dbhh, const float* __restrict__ tW,
    const float* __restrict__ ctxFt, const float* __restrict__ seFt,
    const float* __restrict__ lastT, float* __restrict__ ppt,
    const float* __restrict__ hrd, float* __restrict__ hwr,
    float* __restrict__ lds_h, float* __restrict__ lds_c)
{
    const int tid = threadIdx.x;
    const int b   = tid & 63;
    const int q4  = tid >> 6;
    const int jw  = __builtin_amdgcn_readfirstlane((int)(blockIdx.x * 4 + q4));
    const float* whr = dWhh + (size_t)jw * D;
    const float* whz = dWhh + (size_t)(768 + jw) * D;
    const float* whn = dWhh + (size_t)(1536 + jw) * D;
    const float* wcr = Wc + (size_t)jw * D;
    const float* wcz = Wc + (size_t)(768 + jw) * D;
    const float* wcn = Wc + (size_t)(1536 + jw) * D;
    float cir = 0.f, ciz = 0.f, cin_ = 0.f, ahr = 0.f, ahz = 0.f, ahn = 0.f;
    for (int kc = 0; kc < D; kc += 64) {
        const float4* gh = (const float4*)(hrd + kc * 64);
        float4* lh = (float4*)lds_h;
        #pragma unroll
        for (int it = 0; it < 4; ++it) lh[tid + 256 * it] = gh[tid + 256 * it];
        {
            const float4* cp = (const float4*)(ctxFt + (size_t)b * D + kc + q4 * 16);
            const float4 c0 = cp[0], c1 = cp[1], c2 = cp[2], c3 = cp[3];
            const int k0 = q4 * 16;
            lds_c[(k0 +  0) * 64 + b] = c0.x; lds_c[(k0 +  1) * 64 + b] = c0.y;
            lds_c[(k0 +  2) * 64 + b] = c0.z; lds_c[(k0 +  3) * 64 + b] = c0.w;
            lds_c[(k0 +  4) * 64 + b] = c1.x; lds_c[(k0 +  5) * 64 + b] = c1.y;
            lds_c[(k0 +  6) * 64 + b] = c1.z; lds_c[(k0 +  7) * 64 + b] = c1.w;
            lds_c[(k0 +  8) * 64 + b] = c2.x; lds_c[(k0 +  9) * 64 + b] = c2.y;
            lds_c[(k0 + 10) * 64 + b] = c2.z; lds_c[(k0 + 11) * 64 + b] = c2.w;
            lds_c[(k0 + 12) * 64 + b] = c3.x; lds_c[(k0 + 13) * 64 + b] = c3.y;
            lds_c[(k0 + 14) * 64 + b] = c3.z; lds_c[(k0 + 15) * 64 + b] = c3.w;
        }
        __syncthreads();
        #pragma unroll
        for (int kk = 0; kk < 64; kk += 4) {
            const float4 v0 = *(const float4*)(wcr + kc + kk);
            const float4 v1 = *(const float4*)(wcz + kc + kk);
            const float4 v2 = *(const float4*)(wcn + kc + kk);
            const float4 v3 = *(const float4*)(whr + kc + kk);
            const float4 v4 = *(const float4*)(whz + kc + kk);
            const float4 v5 = *(const float4*)(whn + kc + kk);
            const float c0 = lds_c[(kk + 0) * 64 + b];
            const float c1 = lds_c[(kk + 1) * 64 + b];
            const float c2 = lds_c[(kk + 2) * 64 + b];
            const float c3 = lds_c[(kk + 3) * 64 + b];
            const float h0 = lds_h[(kk + 0) * 64 + b];
            const float h1 = lds_h[(kk + 1) * 64 + b];
            const float h2 = lds_h[(kk + 2) * 64 + b];
            const float h3 = lds_h[(kk + 3) * 64 + b];
            DOT4(cir, v0, c0, c1, c2, c3);
            DOT4(ciz, v1, c0, c1, c2, c3);
            DOT4(cin_, v2, c0, c1, c2, c3);
            DOT4(ahr, v3, h0, h1, h2, h3);
            DOT4(ahz, v4, h0, h1, h2, h3);
            DOT4(ahn, v5, h0, h1, h2, h3);
        }
        __syncthreads();
    }
    const float inv = 1.f / seFt[b];
    const float lst = lastT[b];
    const float gir = cir * inv + W0[jw] * lst + dbih[jw];
    const float giz = ciz * inv + W0[768 + jw] * lst + dbih[768 + jw];
    const float gin = cin_ * inv + W0[1536 + jw] * lst + dbih[1536 + jw];
    const float r = sigf(gir + ahr + dbhh[jw]);
    const float z = sigf(giz + ahz + dbhh[768 + jw]);
    const float n = tanhfast(gin + r * (ahn + dbhh[1536 + jw]));
    const float ho = hrd[jw * 64 + b];
    const float hn = (1.f - z) * n + z * ho;
    stG(hwr + jw * 64 + b, hn);

    __syncthreads();
    lds_h[q4 * 64 + b] = tW[jw] * hn;
    __syncthreads();
    if (tid < 64) {
        const float p = lds_h[tid] + lds_h[64 + tid] + lds_h[128 + tid] + lds_h[192 + tid];
        stG(ppt + (size_t)tid * 192 + blockIdx.x, p);
    }
}

// ---------------- kDecPersist: 4 barriers/step, 512 blocks ----------------
__global__ __launch_bounds__(256) void kDecPersist(
    const float* __restrict__ Wc, const float* __restrict__ W0,
    const float* __restrict__ dWhh, const float* __restrict__ dbih,
    const float* __restrict__ dbhh, const float* __restrict__ tW,
    const float* __restrict__ tb, const float* __restrict__ qW,
    const float* __restrict__ qb,
    const __hip_bfloat16* __restrict__ memB, const __hip_bfloat16* __restrict__ encB,
    const float* __restrict__ pW, const float* __restrict__ pb,
    float* __restrict__ qTu, float* __restrict__ ctxP, float* __restrict__ seP,
    float* __restrict__ ctxC, float* __restrict__ seC,
    float* __restrict__ predP, float* __restrict__ lastP,
    float* __restrict__ hDs, float* __restrict__ out, u32* bar)
{
    __shared__ float smem[8192];
    u32 bars = 0;
    for (int t = 0; t < TDEC; ++t) {
        const float* hr = hDs + (size_t)t * NH;
        float*       hw = hDs + (size_t)(t + 1) * NH;
        if (blockIdx.x < 192)
            dec_q(qW, qb, hr, qTu + (size_t)t * BS * D, smem, smem + 4096);
        else if (blockIdx.x >= 448 && t > 0)
            dec_reduce(predP + (size_t)(t - 1) * 64 * 192, tb,
                       lastP + (size_t)t * 64, out, t - 1, smem);
        gridbar(bar, ++bars);
        dec_attn(qTu + (size_t)t * BS * D, memB, encB, pW, pb, ctxP, seP, smem);
        gridbar(bar, ++bars);
        if (blockIdx.x < 64)
            dec_combine(ctxP, seP, ctxC + (size_t)t * BS * D, seC + (size_t)t * 64);
        gridbar(bar, ++bars);
        if (blockIdx.x < 192)
            dec_cell(Wc, W0, dWhh, dbih, dbhh, tW,
                     ctxC + (size_t)t * BS * D, seC + (size_t)t * 64,
                     lastP + (size_t)t * 64, predP + (size_t)t * 64 * 192,
                     hr, hw, smem, smem + 4096);
        gridbar(bar, ++bars);
    }
    if (blockIdx.x >= 448)
        dec_reduce(predP + (size_t)(TDEC - 1) * 64 * 192, tb,
                   lastP + (size_t)TDEC * 64, out, TDEC - 1, smem);
}

// ---------------- launch ----------------
extern "C" void kernel_launch(void* const* d_in, const int* in_sizes, int n_in,
                              void* d_out, int out_size, void* d_ws, size_t ws_size,
                              hipStream_t stream) {
    const float* x    = (const float*)d_in[0];
    const float* eWih = (const float*)d_in[1];
    const float* eWhh = (const float*)d_in[2];
    const float* ebih = (const float*)d_in[3];
    const float* ebhh = (const float*)d_in[4];
    const float* dWih = (const float*)d_in[5];
    const float* dWhh = (const float*)d_in[6];
    const float* dbih = (const float*)d_in[7];
    const float* dbhh = (const float*)d_in[8];
    const float* qW   = (const float*)d_in[9];
    const float* qb   = (const float*)d_in[10];
    const float* mW   = (const float*)d_in[11];
    const float* mb   = (const float*)d_in[12];
    const float* pW   = (const float*)d_in[13];
    const float* pb   = (const float*)d_in[14];
    const float* tW   = (const float*)d_in[15];
    const float* tb   = (const float*)d_in[16];
    float* out = (float*)d_out;

    char* w = (char*)d_ws;
    auto alloc = [&](size_t bytes) -> char* {
        char* p = w; w += (bytes + 255) & ~(size_t)255; return p;
    };
    // total ~199 MB
    float* Wc    = (float*)alloc((size_t)G3 * D * 4);
    float* W0    = (float*)alloc((size_t)G3 * 4);
    __hip_bfloat16* encB = (__hip_bfloat16*)alloc((size_t)BS * SEQ * D * 2);
    __hip_bfloat16* memB = (__hip_bfloat16*)alloc((size_t)BS * SEQ * D * 2);
    __hip_bfloat16* giB  = (__hip_bfloat16*)alloc((size_t)TCH * G3 * 64 * 2);
    float* hSeq  = (float*)alloc((size_t)(SEQ + 1) * NH * 4);
    float* hDs   = (float*)alloc((size_t)(TDEC + 1) * NH * 4);
    float* qTu   = (float*)alloc((size_t)TDEC * BS * D * 4);
    float* ctxP  = (float*)alloc((size_t)8 * BS * D * 4);
    float* seP   = (float*)alloc(8 * 64 * 4);
    float* ctxC  = (float*)alloc((size_t)TDEC * BS * D * 4);
    float* seC   = (float*)alloc((size_t)TDEC * 64 * 4);
    float* predP = (float*)alloc((size_t)TDEC * 64 * 192 * 4);
    float* lastP = (float*)alloc((size_t)(TDEC + 1) * 64 * 4);
    u32*   barW  = (u32*)alloc((size_t)2 * BAR_SIZE * 4);

    kPrep<<<512, 256, 0, stream>>>(dWih, Wc, W0, hSeq, hDs, lastP, barW);
    kEncPersist<<<NBLK, 256, 0, stream>>>(x, eWih, eWhh, ebih, ebhh, giB, hSeq, encB, barW);
    kGemmMem<<<dim3(12, 300), 256, 0, stream>>>(encB, mW, mb, memB);
    kDecPersist<<<NBLK, 256, 0, stream>>>(Wc, W0, dWhh, dbih, dbhh, tW, tb, qW, qb,
                                          memB, encB, pW, pb, qTu, ctxP, seP, ctxC, seC,
                                          predP, lastP, hDs, out, barW + BAR_SIZE);
}

// Round 7
// 22263.254 us; speedup vs baseline: 2.0775x; 1.0465x over previous
//
#include <hip/hip_runtime.h>
#include <hip/hip_bf16.h>
#include <cstdint>
#include <cstddef>

#define D    768
#define G3   2304
#define BS   64
#define SEQ  300
#define TDEC 100
#define TCH  25          // encoder gi chunk length (12 chunks of 25)
#define NCH  12
#define NBLK 512         // persistent grid: 512 blocks x 256 thr = 2 blocks/CU
#define NH   (D * 64)    // one h-state buffer (fp32 elems)

// ---- barrier region layout (u32 words; lines 128B apart). Two regions: enc, dec. ----
#define R_SLOW_GRP(g)  ((g) * 32)          // 16 slow group counters (MALL)
#define R_SLOW_TOP     512
#define R_SLOW_GEN0    544
#define R_SLOW_GENL(g) (576 + (g) * 32)    // 16 slow release lines (MALL)
#define R_FA_LARR      1088                // fast A: 8 local-L2 arrival lines (+g*32)
#define R_FA_GENL      1344                // fast A: 8 MALL release lines (+g*32)
#define R_FA_TOP       1600
#define R_FA_GEN0      1632
#define R_FB_LARR      1664                // fast B (enc steps): local arrivals
#define R_FB_GENL      1920
#define R_FB_TOP       2176
#define R_FB_GEN0      2208
#define R_PROBE(g)     (2240 + (g) * 32)   // census probe lines (local-L2)
#define R_VOTE         2496
#define R_SIZE         4096                // u32 words per region

typedef unsigned int u32;
typedef unsigned long long u64;

__device__ __forceinline__ float sigf(float x) { return 1.0f / (1.0f + __expf(-x)); }
__device__ __forceinline__ float tanhfast(float x) {
    float e = __expf(2.0f * x);
    return 1.0f - 2.0f / (e + 1.0f);
}
__device__ __forceinline__ void bf2x(u32 u, float& a, float& b) {
    union { u32 i; float f; } xx, yy;
    xx.i = u << 16; yy.i = u & 0xffff0000u; a = xx.f; b = yy.f;
}

#define DOT4(acc, wv, x0, x1, x2, x3) \
    acc = fmaf((wv).x,(x0), fmaf((wv).y,(x1), fmaf((wv).z,(x2), fmaf((wv).w,(x3),(acc)))))

// ---------- coherent (MALL-level) access helpers (proven rounds 2-5) ----------
__device__ __forceinline__ void stG(float* p, float v) {
    __hip_atomic_store(p, v, __ATOMIC_RELAXED, __HIP_MEMORY_SCOPE_AGENT);
}
__device__ __forceinline__ void stG64(u64* p, u64 v) {
    __hip_atomic_store(p, v, __ATOMIC_RELAXED, __HIP_MEMORY_SCOPE_AGENT);
}
__device__ __forceinline__ float ldGf(const float* p) {
    return __hip_atomic_load(p, __ATOMIC_RELAXED, __HIP_MEMORY_SCOPE_AGENT);
}
__device__ __forceinline__ u32 ldGu(const u32* p) {
    return __hip_atomic_load(p, __ATOMIC_RELAXED, __HIP_MEMORY_SCOPE_AGENT);
}
__device__ __forceinline__ u32 f2bfu(float f) {
    __hip_bfloat16 h = __float2bfloat16(f);
    unsigned short s; __builtin_memcpy(&s, &h, 2); return (u32)s;
}
__device__ __forceinline__ float bfsel(u32 w, int sh) {
    union { u32 i; float f; } u; u.i = ((w >> sh) & 0xffffu) << 16; return u.f;
}

// ---------- scoped atomic helpers (pure HIP, no inline asm) ----------
__device__ __forceinline__ u32 add_wg(u32* p, u32 v) {     // executes at local (XCD) L2
    return __hip_atomic_fetch_add(p, v, __ATOMIC_RELAXED, __HIP_MEMORY_SCOPE_WORKGROUP);
}
__device__ __forceinline__ u32 add_ag(u32* p, u32 v) {     // executes at MALL
    return __hip_atomic_fetch_add(p, v, __ATOMIC_RELAXED, __HIP_MEMORY_SCOPE_AGENT);
}
__device__ __forceinline__ void st_ag(u32* p, u32 v) {
    __hip_atomic_store(p, v, __ATOMIC_RELAXED, __HIP_MEMORY_SCOPE_AGENT);
}
__device__ __forceinline__ u32 ld_ag(const u32* p) {
    return __hip_atomic_load(p, __ATOMIC_RELAXED, __HIP_MEMORY_SCOPE_AGENT);
}

// nontemporal bf16x4 load (8B) — keep streamed attn data from evicting L2-resident weights
__device__ __forceinline__ uint2 ldnt2(const __hip_bfloat16* p) {
    u64 v = __builtin_nontemporal_load((const u64*)p);
    uint2 r; r.x = (u32)v; r.y = (u32)(v >> 32); return r;
}

// ---------------- SLOW barrier: round-5 MALL tree (proven fallback) ----------------
__device__ __forceinline__ void bar_slow(u32* B, u32 idx) {
    __builtin_amdgcn_fence(__ATOMIC_RELEASE, "workgroup");
    __syncthreads();
    if (threadIdx.x == 0) {
        const u32 g = blockIdx.x >> 5;
        u32 old = add_ag(&B[R_SLOW_GRP(g)], 1u);
        if (old == idx * 32u - 1u) {
            u32 o2 = add_ag(&B[R_SLOW_TOP], 1u);
            if (o2 == idx * 16u - 1u) {
                st_ag(&B[R_SLOW_GEN0], idx);
            } else {
                while (ld_ag(&B[R_SLOW_GEN0]) < idx) __builtin_amdgcn_s_sleep(4);
            }
            st_ag(&B[R_SLOW_GENL(g)], idx);
        } else {
            while (ld_ag(&B[R_SLOW_GENL(g)]) < idx) __builtin_amdgcn_s_sleep(8);
        }
    }
    __syncthreads();
}

// ---------------- FAST barrier: local-L2 arrival + 8-leader MALL release ----------------
// Valid only if census verified each (blockIdx&7) class shares one XCD L2.
// Arrival: wg-scope RMW at local L2 (~20ns each). Class-last does agent RMW on top;
// top-last publishes gen0; class leaders fan out to per-class MALL gen lines; waiters
// poll their class line with agent relaxed loads (the rounds-2-5-proven mechanism).
__device__ __forceinline__ void bar_fast(u32* R, int larr, int genl, int top, int gen0,
                                         u32 idx, u32 perClass) {
    __builtin_amdgcn_fence(__ATOMIC_RELEASE, "workgroup");
    __syncthreads();
    if (threadIdx.x == 0) {
        const int g = blockIdx.x & 7;
        u32 old = add_wg(&R[larr + g * 32], 1u);
        if (old == idx * perClass - 1u) {          // last arriver of this class
            u32 o2 = add_ag(&R[top], 1u);
            if (o2 == idx * 8u - 1u) {
                st_ag(&R[gen0], idx);
            } else {
                while (ld_ag(&R[gen0]) < idx) __builtin_amdgcn_s_sleep(2);
            }
            st_ag(&R[genl + g * 32], idx);
        } else {
            while (ld_ag(&R[genl + g * 32]) < idx) __builtin_amdgcn_s_sleep(4);
        }
    }
    __syncthreads();
}
#define BAR_FA(R, i, n) bar_fast((R), R_FA_LARR, R_FA_GENL, R_FA_TOP, R_FA_GEN0, (i), (n))
#define BAR_FB(R, i, n) bar_fast((R), R_FB_LARR, R_FB_GENL, R_FB_TOP, R_FB_GEN0, (i), (n))

// ---------------- census: two fetch_add rounds; vote yes iff round-2 old >= 64 ----------------
// old>=64 in round 2 is possible ONLY if this block's L2 copy absorbed all 64 round-1
// increments of its class => class is single-L2. Any split => some block sees <64 =>
// vote<512 => permanent slow fallback. No raw reads, no idempotent-RMW hazard.
__device__ __forceinline__ u32 censusRun(u32* R, u32* sflag) {
    if (threadIdx.x == 0) add_wg(&R[R_PROBE(blockIdx.x & 7)], 1u);
    bar_slow(R, 1);
    if (threadIdx.x == 0) {
        u32 old = add_wg(&R[R_PROBE(blockIdx.x & 7)], 1u);
        add_ag(&R[R_VOTE], (old >= (u32)(NBLK / 8)) ? 1u : 0u);
    }
    bar_slow(R, 2);
    if (threadIdx.x == 0) *sflag = (ld_ag(&R[R_VOTE]) == (u32)NBLK) ? 1u : 0u;
    __syncthreads();
    return *sflag;
}

// ---------------- kPrep ----------------
__global__ __launch_bounds__(256) void kPrep(
    const float* __restrict__ decWih,
    float* __restrict__ Wc, float* __restrict__ W0,
    float* __restrict__ hSeq0, float* __restrict__ hDs0,
    float* __restrict__ lastP, u32* __restrict__ barW)
{
    const int NW = G3 * 769;
    const int NB = 2 * R_SIZE;
    const int TOT = NW + 2 * NH + 64 + NB;
    const int stride = gridDim.x * blockDim.x;
    for (int u = blockIdx.x * blockDim.x + threadIdx.x; u < TOT; u += stride) {
        if (u < NW) {
            int g = u / 769; int c = u % 769;
            float w = decWih[u];
            if (c == 0) W0[g] = w; else Wc[(size_t)g * D + (c - 1)] = w;
        } else if (u < NW + NH) {
            hSeq0[u - NW] = 0.0f;
        } else if (u < NW + 2 * NH) {
            hDs0[u - NW - NH] = 0.0f;
        } else if (u < NW + 2 * NH + 64) {
            lastP[u - NW - 2 * NH] = 0.0f;
        } else {
            barW[u - NW - 2 * NH - 64] = 0;
        }
    }
}

// ---------------- gi tile (round-5 body) ----------------
__device__ __forceinline__ void gi_tile(
    const float* __restrict__ x, const float* __restrict__ Wih,
    __hip_bfloat16* __restrict__ giB, float* __restrict__ As, float* __restrict__ Bs,
    int m0, int tc, int t)
{
    const int tid = threadIdx.x;
    const int lr = tid >> 2;
    const int lk = (tid & 3) * 4;
    const int tm = (tid >> 4) * 4;
    const int tn = (tid & 15) * 4;
    const float tf = (float)t;

    float acc[4][4];
    #pragma unroll
    for (int i = 0; i < 4; ++i)
        #pragma unroll
        for (int j = 0; j < 4; ++j) acc[i][j] = 0.f;

    for (int kc = 0; kc < D; kc += 16) {
        const float4 a4 = *(const float4*)(Wih + (size_t)(m0 + lr) * D + kc + lk);
        float4 b4 = *(const float4*)(x + ((size_t)lr * SEQ + t) * D + kc + lk);
        const int i0 = (kc + lk) >> 1;
        const float dv0 = __expf(-0.0239852614f * (float)i0);
        const float dv1 = __expf(-0.0239852614f * (float)(i0 + 1));
        float s0, c0, s1, c1;
        __sincosf(tf * dv0, &s0, &c0);
        __sincosf(tf * dv1, &s1, &c1);
        b4.x += s0; b4.y += c0; b4.z += s1; b4.w += c1;
        As[(lk + 0) * 64 + lr] = a4.x; As[(lk + 1) * 64 + lr] = a4.y;
        As[(lk + 2) * 64 + lr] = a4.z; As[(lk + 3) * 64 + lr] = a4.w;
        Bs[(lk + 0) * 64 + lr] = b4.x; Bs[(lk + 1) * 64 + lr] = b4.y;
        Bs[(lk + 2) * 64 + lr] = b4.z; Bs[(lk + 3) * 64 + lr] = b4.w;
        __syncthreads();
        #pragma unroll
        for (int k = 0; k < 16; ++k) {
            const float4 av = *(const float4*)(As + k * 64 + tm);
            const float4 bv = *(const float4*)(Bs + k * 64 + tn);
            acc[0][0] = fmaf(av.x, bv.x, acc[0][0]); acc[0][1] = fmaf(av.x, bv.y, acc[0][1]);
            acc[0][2] = fmaf(av.x, bv.z, acc[0][2]); acc[0][3] = fmaf(av.x, bv.w, acc[0][3]);
            acc[1][0] = fmaf(av.y, bv.x, acc[1][0]); acc[1][1] = fmaf(av.y, bv.y, acc[1][1]);
            acc[1][2] = fmaf(av.y, bv.z, acc[1][2]); acc[1][3] = fmaf(av.y, bv.w, acc[1][3]);
            acc[2][0] = fmaf(av.z, bv.x, acc[2][0]); acc[2][1] = fmaf(av.z, bv.y, acc[2][1]);
            acc[2][2] = fmaf(av.z, bv.z, acc[2][2]); acc[2][3] = fmaf(av.z, bv.w, acc[2][3]);
            acc[3][0] = fmaf(av.w, bv.x, acc[3][0]); acc[3][1] = fmaf(av.w, bv.y, acc[3][1]);
            acc[3][2] = fmaf(av.w, bv.z, acc[3][2]); acc[3][3] = fmaf(av.w, bv.w, acc[3][3]);
        }
        __syncthreads();
    }
    #pragma unroll
    for (int i = 0; i < 4; ++i) {
        u32 lo = f2bfu(acc[i][0]) | (f2bfu(acc[i][1]) << 16);
        u32 hi = f2bfu(acc[i][2]) | (f2bfu(acc[i][3]) << 16);
        u64 v = ((u64)hi << 32) | (u64)lo;
        stG64((u64*)(giB + ((size_t)tc * G3 + m0 + tm + i) * 64 + tn), v);
    }
}

// ---------------- encoder recurrence step (round-5 body) ----------------
__device__ __forceinline__ void enc_step(
    const __hip_bfloat16* __restrict__ giT, const float* __restrict__ Whh,
    const float* __restrict__ bih, const float* __restrict__ bhh,
    const float* __restrict__ hrd, float* __restrict__ hwr,
    __hip_bfloat16* __restrict__ encB, int t, float* __restrict__ lds_h)
{
    const int tid = threadIdx.x;
    const int b   = tid & 63;
    const int jw  = __builtin_amdgcn_readfirstlane((int)(blockIdx.x * 4 + (tid >> 6)));

    const float* whr = Whh + (size_t)jw * D;
    const float* whz = Whh + (size_t)(768 + jw) * D;
    const float* whn = Whh + (size_t)(1536 + jw) * D;

    float ahr = 0.f, ahz = 0.f, ahn = 0.f;
    for (int kc = 0; kc < D; kc += 64) {
        const float4* gh = (const float4*)(hrd + kc * 64);
        float4* lh = (float4*)lds_h;
        #pragma unroll
        for (int it = 0; it < 4; ++it) lh[tid + 256 * it] = gh[tid + 256 * it];
        __syncthreads();
        #pragma unroll
        for (int kk = 0; kk < 64; kk += 4) {
            const float4 v3 = *(const float4*)(whr + kc + kk);
            const float4 v4 = *(const float4*)(whz + kc + kk);
            const float4 v5 = *(const float4*)(whn + kc + kk);
            const float h0 = lds_h[(kk + 0) * 64 + b];
            const float h1 = lds_h[(kk + 1) * 64 + b];
            const float h2 = lds_h[(kk + 2) * 64 + b];
            const float h3 = lds_h[(kk + 3) * 64 + b];
            DOT4(ahr, v3, h0, h1, h2, h3);
            DOT4(ahz, v4, h0, h1, h2, h3);
            DOT4(ahn, v5, h0, h1, h2, h3);
        }
        __syncthreads();
    }
    const u32* gp = (const u32*)giT;
    const int bo = b >> 1, sh = (b & 1) << 4;
    const u32 w0 = ldGu(gp + (size_t)jw * 32 + bo);
    const u32 w1 = ldGu(gp + (size_t)(768 + jw) * 32 + bo);
    const u32 w2 = ldGu(gp + (size_t)(1536 + jw) * 32 + bo);
    const float gir = bfsel(w0, sh);
    const float giz = bfsel(w1, sh);
    const float gin = bfsel(w2, sh);
    const float r = sigf(gir + bih[jw] + ahr + bhh[jw]);
    const float z = sigf(giz + bih[768 + jw] + ahz + bhh[768 + jw]);
    const float n = tanhfast(gin + bih[1536 + jw] + r * (ahn + bhh[1536 + jw]));
    const float ho = hrd[jw * 64 + b];
    const float hn = (1.f - z) * n + z * ho;
    stG(hwr + jw * 64 + b, hn);
    encB[((size_t)b * SEQ + t) * D + jw] = __float2bfloat16(hn);
}

// ---------------- kEncPersist ----------------
// fast mode: narrow 192-block step barrier (24/class) + GI for chunk c+1 on blocks
// 192..511 concurrently (double-buffered giB, sealed by a full-512 BAR_FA per chunk).
// slow mode: round-5-equivalent (steps then GI, all barriers full-width).
__global__ __launch_bounds__(256) void kEncPersist(
    const float* __restrict__ x, const float* __restrict__ eWih,
    const float* __restrict__ eWhh, const float* __restrict__ ebih,
    const float* __restrict__ ebhh, __hip_bfloat16* __restrict__ giB,
    float* __restrict__ hSeq, __hip_bfloat16* __restrict__ encB, u32* R)
{
    __shared__ float smem[4096];
    __shared__ u32 sflag;
    const u32 fast = censusRun(R, &sflag);
    const int bid = blockIdx.x;
    const size_t GSZ = (size_t)TCH * G3 * 64;
    u32 si = 2, fE = 0, fS = 0;

    // prologue: GI chunk 0 into buf0 (all blocks)
    for (int job = bid; job < 36 * TCH; job += NBLK)
        gi_tile(x, eWih, giB, smem, smem + 1024, (job % 36) * 64, job / 36, job / 36);
    if (fast) BAR_FA(R, ++fE, 64); else bar_slow(R, ++si);

    for (int c = 0; c < NCH; ++c) {
        __hip_bfloat16* gcur = giB + (size_t)(c & 1) * GSZ;
        __hip_bfloat16* gnxt = giB + (size_t)((c + 1) & 1) * GSZ;
        if (fast) {
            if (bid < 192) {
                for (int tc = 0; tc < TCH; ++tc) {
                    const int t = c * TCH + tc;
                    enc_step(gcur + (size_t)tc * G3 * 64, eWhh, ebih, ebhh,
                             hSeq + (size_t)t * NH, hSeq + (size_t)(t + 1) * NH, encB, t, smem);
                    BAR_FB(R, ++fS, 24);      // only the 192 step blocks
                }
            } else if (c + 1 < NCH) {
                for (int j = bid - 192; j < 36 * TCH; j += 320)
                    gi_tile(x, eWih, gnxt, smem, smem + 1024,
                            (j % 36) * 64, j / 36, (c + 1) * TCH + j / 36);
            }
            BAR_FA(R, ++fE, 64);              // chunk seal: all 512
        } else {
            for (int tc = 0; tc < TCH; ++tc) {
                const int t = c * TCH + tc;
                if (bid < 192)
                    enc_step(gcur + (size_t)tc * G3 * 64, eWhh, ebih, ebhh,
                             hSeq + (size_t)t * NH, hSeq + (size_t)(t + 1) * NH, encB, t, smem);
                bar_slow(R, ++si);
            }
            if (c + 1 < NCH) {
                for (int job = bid; job < 36 * TCH; job += NBLK)
                    gi_tile(x, eWih, gnxt, smem, smem + 1024,
                            (job % 36) * 64, job / 36, (c + 1) * TCH + job / 36);
                bar_slow(R, ++si);
            }
        }
    }
}

// ---------------- kGemmMem (unchanged) ----------------
__global__ __launch_bounds__(256) void kGemmMem(
    const __hip_bfloat16* __restrict__ encB, const float* __restrict__ mW,
    const float* __restrict__ mb, __hip_bfloat16* __restrict__ memB)
{
    __shared__ float As[16 * 64];
    __shared__ float Bs[16 * 64];
    const int tid = threadIdx.x;
    const int m0 = blockIdx.y * 64, n0 = blockIdx.x * 64;
    const int lr = tid >> 2;
    const int lk = (tid & 3) * 4;
    const int tm = (tid >> 4) * 4;
    const int tn = (tid & 15) * 4;

    float acc[4][4];
    #pragma unroll
    for (int i = 0; i < 4; ++i)
        #pragma unroll
        for (int j = 0; j < 4; ++j) acc[i][j] = 0.f;

    for (int kc = 0; kc < D; kc += 16) {
        const uint2 ua = *(const uint2*)(encB + (size_t)(m0 + lr) * D + kc + lk);
        float a0, a1, a2, a3;
        bf2x(ua.x, a0, a1); bf2x(ua.y, a2, a3);
        const float4 b4 = *(const float4*)(mW + (size_t)(n0 + lr) * D + kc + lk);
        As[(lk + 0) * 64 + lr] = a0; As[(lk + 1) * 64 + lr] = a1;
        As[(lk + 2) * 64 + lr] = a2; As[(lk + 3) * 64 + lr] = a3;
        Bs[(lk + 0) * 64 + lr] = b4.x; Bs[(lk + 1) * 64 + lr] = b4.y;
        Bs[(lk + 2) * 64 + lr] = b4.z; Bs[(lk + 3) * 64 + lr] = b4.w;
        __syncthreads();
        #pragma unroll
        for (int k = 0; k < 16; ++k) {
            const float4 av = *(const float4*)(As + k * 64 + tm);
            const float4 bv = *(const float4*)(Bs + k * 64 + tn);
            acc[0][0] = fmaf(av.x, bv.x, acc[0][0]); acc[0][1] = fmaf(av.x, bv.y, acc[0][1]);
            acc[0][2] = fmaf(av.x, bv.z, acc[0][2]); acc[0][3] = fmaf(av.x, bv.w, acc[0][3]);
            acc[1][0] = fmaf(av.y, bv.x, acc[1][0]); acc[1][1] = fmaf(av.y, bv.y, acc[1][1]);
            acc[1][2] = fmaf(av.y, bv.z, acc[1][2]); acc[1][3] = fmaf(av.y, bv.w, acc[1][3]);
            acc[2][0] = fmaf(av.z, bv.x, acc[2][0]); acc[2][1] = fmaf(av.z, bv.y, acc[2][1]);
            acc[2][2] = fmaf(av.z, bv.z, acc[2][2]); acc[2][3] = fmaf(av.z, bv.w, acc[2][3]);
            acc[3][0] = fmaf(av.w, bv.x, acc[3][0]); acc[3][1] = fmaf(av.w, bv.y, acc[3][1]);
            acc[3][2] = fmaf(av.w, bv.z, acc[3][2]); acc[3][3] = fmaf(av.w, bv.w, acc[3][3]);
        }
        __syncthreads();
    }
    const float bb0 = mb[n0 + tn + 0], bb1 = mb[n0 + tn + 1];
    const float bb2 = mb[n0 + tn + 2], bb3 = mb[n0 + tn + 3];
    #pragma unroll
    for (int i = 0; i < 4; ++i) {
        __hip_bfloat16* row = memB + (size_t)(m0 + tm + i) * D + n0 + tn;
        row[0] = __float2bfloat16(acc[i][0] + bb0);
        row[1] = __float2bfloat16(acc[i][1] + bb1);
        row[2] = __float2bfloat16(acc[i][2] + bb2);
        row[3] = __float2bfloat16(acc[i][3] + bb3);
    }
}

// ---------------- decoder phases (round-5 bodies; attn loads now nontemporal) ----------------
__device__ __forceinline__ void dec_q(
    const float* __restrict__ qW, const float* __restrict__ qb,
    const float* __restrict__ hrd, float* __restrict__ qTt,
    float* __restrict__ lds_h, float* __restrict__ lds_t)
{
    const int tid = threadIdx.x;
    const int b   = tid & 63;
    const int wv  = tid >> 6;
    const int jw  = __builtin_amdgcn_readfirstlane((int)(blockIdx.x * 4 + wv));
    const float* w = qW + (size_t)jw * D;
    float acc = 0.f;
    for (int kc = 0; kc < D; kc += 64) {
        const float4* gh = (const float4*)(hrd + kc * 64);
        float4* lh = (float4*)lds_h;
        #pragma unroll
        for (int it = 0; it < 4; ++it) lh[tid + 256 * it] = gh[tid + 256 * it];
        __syncthreads();
        #pragma unroll
        for (int kk = 0; kk < 64; kk += 4) {
            const float4 w4 = *(const float4*)(w + kc + kk);
            acc = fmaf(w4.x, lds_h[(kk + 0) * 64 + b], acc);
            acc = fmaf(w4.y, lds_h[(kk + 1) * 64 + b], acc);
            acc = fmaf(w4.z, lds_h[(kk + 2) * 64 + b], acc);
            acc = fmaf(w4.w, lds_h[(kk + 3) * 64 + b], acc);
        }
        __syncthreads();
    }
    lds_t[b * 4 + wv] = acc + qb[jw];
    __syncthreads();
    if (tid < 128) {
        const int bb = tid >> 1, hf = (tid & 1) * 2;
        float2 v; v.x = lds_t[bb * 4 + hf]; v.y = lds_t[bb * 4 + hf + 1];
        u64 uv; __builtin_memcpy(&uv, &v, 8);
        stG64((u64*)(qTt + (size_t)bb * D + blockIdx.x * 4 + hf), uv);
    }
}

__device__ __forceinline__ void dec_attn(
    const float* __restrict__ qTt, const __hip_bfloat16* __restrict__ memB,
    const __hip_bfloat16* __restrict__ encB, const float* __restrict__ pW,
    const float* __restrict__ pb, float* __restrict__ ctxP, float* __restrict__ seP,
    float* __restrict__ sm)
{
    const int tid = threadIdx.x;
    const int b  = blockIdx.x & 63;
    const int ch = blockIdx.x >> 6;          // 0..7
    float* s_q  = sm;
    float* s_pw = sm + 768;
    float* s_cx = sm + 1536;
    float* s_se = sm + 2304;
    for (int i = tid; i < 768; i += 256) {
        s_q[i]  = qTt[(size_t)b * D + i];
        s_pw[i] = pW[i];
        s_cx[i] = 0.f;
    }
    if (tid == 0) s_se[0] = 0.f;
    __syncthreads();
    const int lane = tid & 63;
    const int wv   = tid >> 6;
    const int d0_0 = lane * 4, d0_1 = 256 + lane * 4, d0_2 = 512 + lane * 4;
    const float4 qv0 = *(const float4*)(s_q + d0_0);
    const float4 qv1 = *(const float4*)(s_q + d0_1);
    const float4 qv2 = *(const float4*)(s_q + d0_2);
    const float4 pv0 = *(const float4*)(s_pw + d0_0);
    const float4 pv1 = *(const float4*)(s_pw + d0_1);
    const float4 pv2 = *(const float4*)(s_pw + d0_2);
    float cacc[12];
    #pragma unroll
    for (int i = 0; i < 12; ++i) cacc[i] = 0.f;
    float seacc = 0.f;
    const float pbv = pb[0];
    const size_t rowb = (size_t)b * SEQ;
    int s = ch + 8 * wv;
    uint2 mu0, mu1, mu2, eu0, eu1, eu2;
    if (s < SEQ) {
        const __hip_bfloat16* mrow = memB + (rowb + s) * D;
        const __hip_bfloat16* erow = encB + (rowb + s) * D;
        mu0 = ldnt2(mrow + d0_0); mu1 = ldnt2(mrow + d0_1); mu2 = ldnt2(mrow + d0_2);
        eu0 = ldnt2(erow + d0_0); eu1 = ldnt2(erow + d0_1); eu2 = ldnt2(erow + d0_2);
    }
    while (s < SEQ) {
        const int sn = s + 32;
        const bool pf = sn < SEQ;
        uint2 nm0, nm1, nm2, ne0, ne1, ne2;
        if (pf) {
            const __hip_bfloat16* mrow = memB + (rowb + sn) * D;
            const __hip_bfloat16* erow = encB + (rowb + sn) * D;
            nm0 = ldnt2(mrow + d0_0); nm1 = ldnt2(mrow + d0_1); nm2 = ldnt2(mrow + d0_2);
            ne0 = ldnt2(erow + d0_0); ne1 = ldnt2(erow + d0_1); ne2 = ldnt2(erow + d0_2);
        }
        float lp = 0.f;
        float m0, m1, m2, m3;
        bf2x(mu0.x, m0, m1); bf2x(mu0.y, m2, m3);
        lp = fmaf(pv0.x, tanhfast(m0 + qv0.x), lp);
        lp = fmaf(pv0.y, tanhfast(m1 + qv0.y), lp);
        lp = fmaf(pv0.z, tanhfast(m2 + qv0.z), lp);
        lp = fmaf(pv0.w, tanhfast(m3 + qv0.w), lp);
        bf2x(mu1.x, m0, m1); bf2x(mu1.y, m2, m3);
        lp = fmaf(pv1.x, tanhfast(m0 + qv1.x), lp);
        lp = fmaf(pv1.y, tanhfast(m1 + qv1.y), lp);
        lp = fmaf(pv1.z, tanhfast(m2 + qv1.z), lp);
        lp = fmaf(pv1.w, tanhfast(m3 + qv1.w), lp);
        bf2x(mu2.x, m0, m1); bf2x(mu2.y, m2, m3);
        lp = fmaf(pv2.x, tanhfast(m0 + qv2.x), lp);
        lp = fmaf(pv2.y, tanhfast(m1 + qv2.y), lp);
        lp = fmaf(pv2.z, tanhfast(m2 + qv2.z), lp);
        lp = fmaf(pv2.w, tanhfast(m3 + qv2.w), lp);
        #pragma unroll
        for (int o = 32; o > 0; o >>= 1) lp += __shfl_xor(lp, o, 64);
        const float e = __expf(lp + pbv);
        seacc += e;
        float e0, e1, e2, e3;
        bf2x(eu0.x, e0, e1); bf2x(eu0.y, e2, e3);
        cacc[0] = fmaf(e, e0, cacc[0]); cacc[1] = fmaf(e, e1, cacc[1]);
        cacc[2] = fmaf(e, e2, cacc[2]); cacc[3] = fmaf(e, e3, cacc[3]);
        bf2x(eu1.x, e0, e1); bf2x(eu1.y, e2, e3);
        cacc[4] = fmaf(e, e0, cacc[4]); cacc[5] = fmaf(e, e1, cacc[5]);
        cacc[6] = fmaf(e, e2, cacc[6]); cacc[7] = fmaf(e, e3, cacc[7]);
        bf2x(eu2.x, e0, e1); bf2x(eu2.y, e2, e3);
        cacc[8]  = fmaf(e, e0, cacc[8]);  cacc[9]  = fmaf(e, e1, cacc[9]);
        cacc[10] = fmaf(e, e2, cacc[10]); cacc[11] = fmaf(e, e3, cacc[11]);
        if (pf) { mu0 = nm0; mu1 = nm1; mu2 = nm2; eu0 = ne0; eu1 = ne1; eu2 = ne2; }
        s = sn;
    }
    #pragma unroll
    for (int g = 0; g < 3; ++g) {
        const int d0 = g * 256 + lane * 4;
        atomicAdd(&s_cx[d0 + 0], cacc[g * 4 + 0]);
        atomicAdd(&s_cx[d0 + 1], cacc[g * 4 + 1]);
        atomicAdd(&s_cx[d0 + 2], cacc[g * 4 + 2]);
        atomicAdd(&s_cx[d0 + 3], cacc[g * 4 + 3]);
    }
    if (lane == 0) atomicAdd(&s_se[0], seacc);
    __syncthreads();
    float* crow = ctxP + (size_t)(ch * 64 + b) * D;
    for (int i = tid; i < 768; i += 256) stG(crow + i, s_cx[i]);
    if (tid == 0) stG(seP + ch * 64 + b, s_se[0]);
}

__device__ __forceinline__ void dec_combine(
    const float* __restrict__ ctxP, const float* __restrict__ seP,
    float* __restrict__ ctxCt, float* __restrict__ seCt)
{
    const int b = blockIdx.x;           // < 64
    const int tid = threadIdx.x;
    for (int i = tid; i < 768; i += 256) {
        float s = 0.f;
        #pragma unroll
        for (int ch = 0; ch < 8; ++ch)
            s += ldGf(ctxP + (size_t)(ch * 64 + b) * D + i);
        stG(ctxCt + (size_t)b * D + i, s);
    }
    if (tid == 0) {
        float s = 0.f;
        #pragma unroll
        for (int ch = 0; ch < 8; ++ch) s += ldGf(seP + ch * 64 + b);
        stG(seCt + b, s);
    }
}

__device__ __forceinline__ void dec_reduce(
    const float* __restrict__ ppt, const float* __restrict__ tb,
    float* __restrict__ lastN, float* __restrict__ out, int t, float* __restrict__ sm)
{
    const int b = blockIdx.x - 448;
    const int tid = threadIdx.x;
    float v = 0.f;
    if (tid < 192) v = ppt[(size_t)b * 192 + tid];
    #pragma unroll
    for (int o = 32; o > 0; o >>= 1) v += __shfl_xor(v, o, 64);
    if ((tid & 63) == 0) sm[tid >> 6] = v;
    __syncthreads();
    if (tid == 0) {
        const float p = sm[0] + sm[1] + sm[2] + sm[3] + tb[0];
        out[(size_t)b * TDEC + t] = p;
        stG(lastN + b, p);
    }
    __syncthreads();
}

__device__ __forceinline__ void dec_cell(
    const float* __restrict__ Wc, const float* __restrict__ W0,
    const float* __restrict__ dWhh, const float* __restrict__ dbih,
    const float* __restrict__ dbhh, const float* __restrict__ tW,
    const float* __restrict__ ctxFt, const float* __restrict__ seFt,
    const float* __restrict__ lastT, float* __restrict__ ppt,
    const float* __restrict__ hrd, float* __restrict__ hwr,
    float* __restrict__ lds_h, float* __restrict__ lds_c)
{
    const int tid = threadIdx.x;
    const int b   = tid & 63;
    const int q4  = tid >> 6;
    const int jw  = __builtin_amdgcn_readfirstlane((int)(blockIdx.x * 4 + q4));
    const float* whr = dWhh + (size_t)jw * D;
    const float* whz = dWhh + (size_t)(768 + jw) * D;
    const float* whn = dWhh + (size_t)(1536 + jw) * D;
    const float* wcr = Wc + (size_t)jw * D;
    const float* wcz = Wc + (size_t)(768 + jw) * D;
    const float* wcn = Wc + (size_t)(1536 + jw) * D;
    float cir = 0.f, ciz = 0.f, cin_ = 0.f, ahr = 0.f, ahz = 0.f, ahn = 0.f;
    for (int kc = 0; kc < D; kc += 64) {
        const float4* gh = (const float4*)(hrd + kc * 64);
        float4* lh = (float4*)lds_h;
        #pragma unroll
        for (int it = 0; it < 4; ++it) lh[tid + 256 * it] = gh[tid + 256 * it];
        {
            const float4* cp = (const float4*)(ctxFt + (size_t)b * D + kc + q4 * 16);
            const float4 c0 = cp[0], c1 = cp[1], c2 = cp[2], c3 = cp[3];
            const int k0 = q4 * 16;
            lds_c[(k0 +  0) * 64 + b] = c0.x; lds_c[(k0 +  1) * 64 + b] = c0.y;
            lds_c[(k0 +  2) * 64 + b] = c0.z; lds_c[(k0 +  3) * 64 + b] = c0.w;
            lds_c[(k0 +  4) * 64 + b] = c1.x; lds_c[(k0 +  5) * 64 + b] = c1.y;
            lds_c[(k0 +  6) * 64 + b] = c1.z; lds_c[(k0 +  7) * 64 + b] = c1.w;
            lds_c[(k0 +  8) * 64 + b] = c2.x; lds_c[(k0 +  9) * 64 + b] = c2.y;
            lds_c[(k0 + 10) * 64 + b] = c2.z; lds_c[(k0 + 11) * 64 + b] = c2.w;
            lds_c[(k0 + 12) * 64 + b] = c3.x; lds_c[(k0 + 13) * 64 + b] = c3.y;
            lds_c[(k0 + 14) * 64 + b] = c3.z; lds_c[(k0 + 15) * 64 + b] = c3.w;
        }
        __syncthreads();
        #pragma unroll
        for (int kk = 0; kk < 64; kk += 4) {
            const float4 v0 = *(const float4*)(wcr + kc + kk);
            const float4 v1 = *(const float4*)(wcz + kc + kk);
            const float4 v2 = *(const float4*)(wcn + kc + kk);
            const float4 v3 = *(const float4*)(whr + kc + kk);
            const float4 v4 = *(const float4*)(whz + kc + kk);
            const float4 v5 = *(const float4*)(whn + kc + kk);
            const float c0 = lds_c[(kk + 0) * 64 + b];
            const float c1 = lds_c[(kk + 1) * 64 + b];
            const float c2 = lds_c[(kk + 2) * 64 + b];
            const float c3 = lds_c[(kk + 3) * 64 + b];
            const float h0 = lds_h[(kk + 0) * 64 + b];
            const float h1 = lds_h[(kk + 1) * 64 + b];
            const float h2 = lds_h[(kk + 2) * 64 + b];
            const float h3 = lds_h[(kk + 3) * 64 + b];
            DOT4(cir, v0, c0, c1, c2, c3);
            DOT4(ciz, v1, c0, c1, c2, c3);
            DOT4(cin_, v2, c0, c1, c2, c3);
            DOT4(ahr, v3, h0, h1, h2, h3);
            DOT4(ahz, v4, h0, h1, h2, h3);
            DOT4(ahn, v5, h0, h1, h2, h3);
        }
        __syncthreads();
    }
    const float inv = 1.f / seFt[b];
    const float lst = lastT[b];
    const float gir = cir * inv + W0[jw] * lst + dbih[jw];
    const float giz = ciz * inv + W0[768 + jw] * lst + dbih[768 + jw];
    const float gin = cin_ * inv + W0[1536 + jw] * lst + dbih[1536 + jw];
    const float r = sigf(gir + ahr + dbhh[jw]);
    const float z = sigf(giz + ahz + dbhh[768 + jw]);
    const float n = tanhfast(gin + r * (ahn + dbhh[1536 + jw]));
    const float ho = hrd[jw * 64 + b];
    const float hn = (1.f - z) * n + z * ho;
    stG(hwr + jw * 64 + b, hn);

    __syncthreads();
    lds_h[q4 * 64 + b] = tW[jw] * hn;
    __syncthreads();
    if (tid < 64) {
        const float p = lds_h[tid] + lds_h[64 + tid] + lds_h[128 + tid] + lds_h[192 + tid];
        stG(ppt + (size_t)tid * 192 + blockIdx.x, p);
    }
}

// ---------------- kDecPersist ----------------
__global__ __launch_bounds__(256) void kDecPersist(
    const float* __restrict__ Wc, const float* __restrict__ W0,
    const float* __restrict__ dWhh, const float* __restrict__ dbih,
    const float* __restrict__ dbhh, const float* __restrict__ tW,
    const float* __restrict__ tb, const float* __restrict__ qW,
    const float* __restrict__ qb,
    const __hip_bfloat16* __restrict__ memB, const __hip_bfloat16* __restrict__ encB,
    const float* __restrict__ pW, const float* __restrict__ pb,
    float* __restrict__ qTu, float* __restrict__ ctxP, float* __restrict__ seP,
    float* __restrict__ ctxC, float* __restrict__ seC,
    float* __restrict__ predP, float* __restrict__ lastP,
    float* __restrict__ hDs, float* __restrict__ out, u32* R)
{
    __shared__ float smem[8192];
    __shared__ u32 sflag;
    const u32 fast = censusRun(R, &sflag);
    u32 si = 2, fA = 0;
    for (int t = 0; t < TDEC; ++t) {
        const float* hr = hDs + (size_t)t * NH;
        float*       hw = hDs + (size_t)(t + 1) * NH;
        if (blockIdx.x < 192)
            dec_q(qW, qb, hr, qTu + (size_t)t * BS * D, smem, smem + 4096);
        else if (blockIdx.x >= 448 && t > 0)
            dec_reduce(predP + (size_t)(t - 1) * 64 * 192, tb,
                       lastP + (size_t)t * 64, out, t - 1, smem);
        if (fast) BAR_FA(R, ++fA, 64); else bar_slow(R, ++si);
        dec_attn(qTu + (size_t)t * BS * D, memB, encB, pW, pb, ctxP, seP, smem);
        if (fast) BAR_FA(R, ++fA, 64); else bar_slow(R, ++si);
        if (blockIdx.x < 64)
            dec_combine(ctxP, seP, ctxC + (size_t)t * BS * D, seC + (size_t)t * 64);
        if (fast) BAR_FA(R, ++fA, 64); else bar_slow(R, ++si);
        if (blockIdx.x < 192)
            dec_cell(Wc, W0, dWhh, dbih, dbhh, tW,
                     ctxC + (size_t)t * BS * D, seC + (size_t)t * 64,
                     lastP + (size_t)t * 64, predP + (size_t)t * 64 * 192,
                     hr, hw, smem, smem + 4096);
        if (fast) BAR_FA(R, ++fA, 64); else bar_slow(R, ++si);
    }
    if (blockIdx.x >= 448)
        dec_reduce(predP + (size_t)(TDEC - 1) * 64 * 192, tb,
                   lastP + (size_t)TDEC * 64, out, TDEC - 1, smem);
}

// ---------------- launch ----------------
extern "C" void kernel_launch(void* const* d_in, const int* in_sizes, int n_in,
                              void* d_out, int out_size, void* d_ws, size_t ws_size,
                              hipStream_t stream) {
    const float* x    = (const float*)d_in[0];
    const float* eWih = (const float*)d_in[1];
    const float* eWhh = (const float*)d_in[2];
    const float* ebih = (const float*)d_in[3];
    const float* ebhh = (const float*)d_in[4];
    const float* dWih = (const float*)d_in[5];
    const float* dWhh = (const float*)d_in[6];
    const float* dbih = (const float*)d_in[7];
    const float* dbhh = (const float*)d_in[8];
    const float* qW   = (const float*)d_in[9];
    const float* qb   = (const float*)d_in[10];
    const float* mW   = (const float*)d_in[11];
    const float* mb   = (const float*)d_in[12];
    const float* pW   = (const float*)d_in[13];
    const float* pb   = (const float*)d_in[14];
    const float* tW   = (const float*)d_in[15];
    const float* tb   = (const float*)d_in[16];
    float* out = (float*)d_out;

    char* w = (char*)d_ws;
    auto alloc = [&](size_t bytes) -> char* {
        char* p = w; w += (bytes + 255) & ~(size_t)255; return p;
    };
    // total ~207 MB
    float* Wc    = (float*)alloc((size_t)G3 * D * 4);
    float* W0    = (float*)alloc((size_t)G3 * 4);
    __hip_bfloat16* encB = (__hip_bfloat16*)alloc((size_t)BS * SEQ * D * 2);
    __hip_bfloat16* memB = (__hip_bfloat16*)alloc((size_t)BS * SEQ * D * 2);
    __hip_bfloat16* giB  = (__hip_bfloat16*)alloc((size_t)2 * TCH * G3 * 64 * 2);  // double buffer
    float* hSeq  = (float*)alloc((size_t)(SEQ + 1) * NH * 4);
    float* hDs   = (float*)alloc((size_t)(TDEC + 1) * NH * 4);
    float* qTu   = (float*)alloc((size_t)TDEC * BS * D * 4);
    float* ctxP  = (float*)alloc((size_t)8 * BS * D * 4);
    float* seP   = (float*)alloc(8 * 64 * 4);
    float* ctxC  = (float*)alloc((size_t)TDEC * BS * D * 4);
    float* seC   = (float*)alloc((size_t)TDEC * 64 * 4);
    float* predP = (float*)alloc((size_t)TDEC * 64 * 192 * 4);
    float* lastP = (float*)alloc((size_t)(TDEC + 1) * 64 * 4);
    u32*   barW  = (u32*)alloc((size_t)2 * R_SIZE * 4);   // region 0 = enc, region 1 = dec

    kPrep<<<512, 256, 0, stream>>>(dWih, Wc, W0, hSeq, hDs, lastP, barW);
    kEncPersist<<<NBLK, 256, 0, stream>>>(x, eWih, eWhh, ebih, ebhh, giB, hSeq, encB, barW);
    kGemmMem<<<dim3(12, 300), 256, 0, stream>>>(encB, mW, mb, memB);
    kDecPersist<<<NBLK, 256, 0, stream>>>(Wc, W0, dWhh, dbih, dbhh, tW, tb, qW, qb,
                                          memB, encB, pW, pb, qTu, ctxP, seP, ctxC, seC,
                                          predP, lastP, hDs, out, barW + R_SIZE);
}